// Round 12
// baseline (391.493 us; speedup 1.0000x reference)
//
#include <hip/hip_runtime.h>

constexpr int NN = 100000;   // nodes
constexpr int NE = 1600000;  // edges
constexpr int NBUCK = 782;   // ceil(NN/128)
constexpr int CGRID = 98;    // count/scatter blocks (98*16384 >= NE)
constexpr size_t SLSZ = (size_t)NN * 32;  // bytes per 32B column-slice

typedef __attribute__((ext_vector_type(4))) float  f32x4;
typedef __attribute__((ext_vector_type(2))) float  f32x2;
typedef __attribute__((ext_vector_type(8))) short  bf16x8;

__device__ __forceinline__ float bf2f(unsigned short u) {
  union { unsigned int i; float f; } c;
  c.i = ((unsigned int)u) << 16;
  return c.f;
}
__device__ __forceinline__ short f2bf(float f) {
  union { float f; unsigned int i; } c; c.f = f;
  unsigned int i = c.i + 0x7fffu + ((c.i >> 16) & 1u);
  return (short)(i >> 16);
}
__device__ __forceinline__ unsigned char f2fp8(float f) {
  int w = __builtin_amdgcn_cvt_pk_fp8_f32(f, 0.f, 0, false);
  return (unsigned char)(w & 0xff);
}
__device__ __forceinline__ void up4(int wv, float* f) {
  f32x2 a = __builtin_amdgcn_cvt_pk_f32_fp8(wv, false);
  f32x2 b = __builtin_amdgcn_cvt_pk_f32_fp8(wv, true);
  f[0] = a[0]; f[1] = a[1]; f[2] = b[0]; f[3] = b[1];
}

// async global->LDS, 16B per lane; LDS dest is wave-uniform base + lane*16
__device__ __forceinline__ void gload16(const void* g, void* l) {
  __builtin_amdgcn_global_load_lds(
      (const __attribute__((address_space(1))) unsigned int*)g,
      (__attribute__((address_space(3))) unsigned int*)l, 16, 0, 0);
}

// ---- edge dtype detection + stats zeroing ----
__global__ void k_detect(const int* __restrict__ ew, int* __restrict__ flag,
                         float* __restrict__ zst) {
  __shared__ int bad;
  if (threadIdx.x == 0) bad = 0;
  for (int i = threadIdx.x; i < 1024; i += 256) zst[i] = 0.f;
  __syncthreads();
  int nz = 0;
  for (int i = threadIdx.x; i < 2048; i += 256) nz |= ew[2 * i + 1];
  if (nz) atomicOr(&bad, 1);
  __syncthreads();
  if (threadIdx.x == 0) *flag = (bad == 0) ? 1 : 0;
}

// ---- weights: W1,W2 -> fp8 transposed; Wl1 -> bf16 T; Wl3 -> bf16 [16][128] ----
__global__ void k_cvtW(const float* __restrict__ W1, const float* __restrict__ W2,
                       const float* __restrict__ Wl1, const float* __restrict__ Wl3,
                       unsigned char* __restrict__ W1T8, unsigned char* __restrict__ W2T8,
                       short* __restrict__ Wl1T, short* __restrict__ Wl3T) {
  int b = blockIdx.x, t = threadIdx.x;
  if (b < 256)       W1T8[b * 256 + t]       = f2fp8(W1[t * 256 + b]);
  else if (b < 512){ int n = b - 256; W2T8[n * 256 + t] = f2fp8(W2[t * 256 + n]); }
  else if (b < 640){ int n = b - 512; Wl1T[n * 256 + t] = f2bf(Wl1[t * 128 + n]); }
  else {
    if (t < 128) {
#pragma unroll
      for (int c = 0; c < 16; ++c)
        Wl3T[c * 128 + t] = (c < 10) ? f2bf(Wl3[t * 10 + c]) : (short)0;
    }
  }
}

// ---- x (f32) -> fp8, SLICED layout [8][NN][32B] (slice = 32-col group) ----
__global__ void k_cvtX(const float* __restrict__ x, unsigned char* __restrict__ xs) {
  int c = blockIdx.x * 256 + threadIdx.x;  // 3.2M chunks of 8 cols, grid exact
  int n = c >> 5, cg = c & 31;             // node, col-group(8 cols)
  float4 a = ((const float4*)x)[2 * (size_t)c];
  float4 b = ((const float4*)x)[2 * (size_t)c + 1];
  int p0 = 0, p1 = 0;
  p0 = __builtin_amdgcn_cvt_pk_fp8_f32(a.x, a.y, p0, false);
  p0 = __builtin_amdgcn_cvt_pk_fp8_f32(a.z, a.w, p0, true);
  p1 = __builtin_amdgcn_cvt_pk_fp8_f32(b.x, b.y, p1, false);
  p1 = __builtin_amdgcn_cvt_pk_fp8_f32(b.z, b.w, p1, true);
  int slice = cg >> 2;
  *(int2*)(xs + (size_t)slice * SLSZ + (size_t)n * 32 + (cg & 3) * 8) = make_int2(p0, p1);
}

// ---- pass 1: per-block bucket histogram (no global atomics) ----
__global__ __launch_bounds__(1024) void k_count(const int* __restrict__ ew,
                                                const int* __restrict__ flag,
                                                int* __restrict__ cntmat) {
  __shared__ int lcnt[NBUCK];
  int m64 = *flag;
  int t = threadIdx.x;
  for (int i = t; i < NBUCK; i += 1024) lcnt[i] = 0;
  __syncthreads();
  int base = blockIdx.x * 16384;
#pragma unroll
  for (int u = 0; u < 16; u++) {
    int e = base + u * 1024 + t;
    if (e < NE) {
      int d = m64 ? ew[2 * (NE + e)] : ew[NE + e];
      atomicAdd(&lcnt[d >> 7], 1);
    }
  }
  __syncthreads();
  for (int i = t; i < NBUCK; i += 1024) cntmat[blockIdx.x * NBUCK + i] = lcnt[i];
}

// ---- pass 2: column scan -> per-(block,bucket) positions + bucket bases ----
__global__ __launch_bounds__(1024) void k_colscan(int* __restrict__ cntmat,
                                                  int* __restrict__ bases,
                                                  int* __restrict__ off_) {
  __shared__ int tot[1024];
  int t = threadIdx.x;
  int sum = 0;
  if (t < NBUCK) {
    for (int g = 0; g < CGRID; g++) sum += cntmat[g * NBUCK + t];
    tot[t] = sum;
  }
  __syncthreads();
  int v = (t < NBUCK) ? sum : 0;
  for (int o = 1; o < 1024; o <<= 1) {
    int u = (t >= o && t < NBUCK) ? tot[t - o] : 0;
    __syncthreads();
    if (t < NBUCK) tot[t] += u;
    __syncthreads();
  }
  if (t < NBUCK) {
    int b = tot[t] - v;  // exclusive
    bases[t] = b;
    int run = b;
    for (int g = 0; g < CGRID; g++) {
      int c = cntmat[g * NBUCK + t];
      cntmat[g * NBUCK + t] = run;
      run += c;
    }
  }
  if (t == NBUCK) bases[NBUCK] = NE;
  if (t == NBUCK + 1) off_[NN] = NE;
}

// ---- pass 3: dense bucketed scatter of packed (src | ld<<17) ----
__global__ __launch_bounds__(1024) void k_scatter(const int* __restrict__ ew,
                                                  const int* __restrict__ flag,
                                                  const int* __restrict__ cntmat,
                                                  int* __restrict__ pairs) {
  __shared__ int lcur[NBUCK];
  int m64 = *flag;
  int t = threadIdx.x;
  for (int i = t; i < NBUCK; i += 1024) lcur[i] = cntmat[blockIdx.x * NBUCK + i];
  __syncthreads();
  int base = blockIdx.x * 16384;
#pragma unroll
  for (int u = 0; u < 16; u++) {
    int e = base + u * 1024 + t;
    if (e < NE) {
      int d = m64 ? ew[2 * (NE + e)] : ew[NE + e];
      int s = m64 ? ew[2 * e] : ew[e];
      int slot = atomicAdd(&lcur[d >> 7], 1);
      pairs[slot] = s | ((d & 127) << 17);
    }
  }
}

// ---- pass 4: per-bucket counting sort in LDS -> off_ + csr ----
__global__ __launch_bounds__(256) void k_bsort(const int* __restrict__ pairs,
                                               const int* __restrict__ bases,
                                               int* __restrict__ off_,
                                               int* __restrict__ csr) {
  __shared__ int lcnt[128], lofs[128], lcur[128];
  int b = blockIdx.x, t = threadIdx.x;
  int s0 = bases[b], s1 = bases[b + 1];
  if (t < 128) lcnt[t] = 0;
  __syncthreads();
  for (int j = s0 + t; j < s1; j += 256) atomicAdd(&lcnt[(pairs[j] >> 17) & 127], 1);
  __syncthreads();
  int v = (t < 128) ? lcnt[t] : 0;
  if (t < 128) lofs[t] = v;
  __syncthreads();
  for (int o = 1; o < 128; o <<= 1) {
    int u = (t >= o && t < 128) ? lofs[t - o] : 0;
    __syncthreads();
    if (t < 128) lofs[t] += u;
    __syncthreads();
  }
  if (t < 128) {
    int ex = lofs[t] - v;  // exclusive
    lcur[t] = ex;
    int node = b * 128 + t;
    if (node < NN) off_[node] = s0 + ex;
  }
  __syncthreads();
  for (int j = s0 + t; j < s1; j += 256) {
    int p = pairs[j];
    int slot = atomicAdd(&lcur[(p >> 17) & 127], 1);
    csr[s0 + slot] = p & 0x1FFFF;
  }
}

// ============================================================================
// XCD-sliced gather, NODE-PER-WAVE (fixes agg3's degree divergence).
// Block = 4 nodes x 1 slice; slice = bid & 7 (XCD-pinned -> 3.2MB slice
// L2-resident). Wave = 1 node: lane (sub=lane>>3, part=lane&7) reads neighbor
// j+sub's bytes [part*4, part*4+4) -> per iter 1 csr read + 1 x read covers 8
// neighbors x 32B. Guard only on final iter; shfl_xor(8/16/32) reduces subs.
// ============================================================================
__global__ __launch_bounds__(256) void k_agg4(const unsigned char* __restrict__ xs,
                                              const int* __restrict__ off_,
                                              const int* __restrict__ csr,
                                              unsigned char* __restrict__ hs) {
  int slice = blockIdx.x & 7;
  int grp = blockIdx.x >> 3;               // 0..24999
  int lane = threadIdx.x & 63;
  int sub = lane >> 3, part = lane & 7;
  int node = grp * 4 + (threadIdx.x >> 6); // exact: 25000*4 = NN
  const unsigned char* xb = xs + (size_t)slice * SLSZ;
  size_t po = (size_t)part * 4;
  int s0 = off_[node], s1 = off_[node + 1];
  float a0 = 0.f, a1 = 0.f, a2 = 0.f, a3 = 0.f;
  if (sub == 0) {
    int sw = *(const int*)(xb + (size_t)node * 32 + po);
    f32x2 lo = __builtin_amdgcn_cvt_pk_f32_fp8(sw, false);
    f32x2 hi = __builtin_amdgcn_cvt_pk_f32_fp8(sw, true);
    a0 = lo[0]; a1 = lo[1]; a2 = hi[0]; a3 = hi[1];
  }
  int j = s0;
  // main: full 16-neighbor double-iterations (2 loads in flight)
  for (; j + 16 <= s1; j += 16) {
    int id0 = csr[j + sub];
    int id1 = csr[j + 8 + sub];
    int w0 = *(const int*)(xb + (size_t)id0 * 32 + po);
    int w1 = *(const int*)(xb + (size_t)id1 * 32 + po);
    f32x2 lo0 = __builtin_amdgcn_cvt_pk_f32_fp8(w0, false);
    f32x2 hi0 = __builtin_amdgcn_cvt_pk_f32_fp8(w0, true);
    a0 += lo0[0]; a1 += lo0[1]; a2 += hi0[0]; a3 += hi0[1];
    f32x2 lo1 = __builtin_amdgcn_cvt_pk_f32_fp8(w1, false);
    f32x2 hi1 = __builtin_amdgcn_cvt_pk_f32_fp8(w1, true);
    a0 += lo1[0]; a1 += lo1[1]; a2 += hi1[0]; a3 += hi1[1];
  }
  // tail: up to 15 neighbors, guard per 8-group
  for (; j < s1; j += 8) {
    int jj = j + sub;
    bool v = jj < s1;
    int id = v ? csr[jj] : csr[s0];
    int wv = *(const int*)(xb + (size_t)id * 32 + po);
    if (v) {
      f32x2 lo = __builtin_amdgcn_cvt_pk_f32_fp8(wv, false);
      f32x2 hi = __builtin_amdgcn_cvt_pk_f32_fp8(wv, true);
      a0 += lo[0]; a1 += lo[1]; a2 += hi[0]; a3 += hi[1];
    }
  }
  // reduce across the 8 sub-groups (lane bits 3,4,5)
  a0 += __shfl_xor(a0, 8);  a1 += __shfl_xor(a1, 8);
  a2 += __shfl_xor(a2, 8);  a3 += __shfl_xor(a3, 8);
  a0 += __shfl_xor(a0, 16); a1 += __shfl_xor(a1, 16);
  a2 += __shfl_xor(a2, 16); a3 += __shfl_xor(a3, 16);
  a0 += __shfl_xor(a0, 32); a1 += __shfl_xor(a1, 32);
  a2 += __shfl_xor(a2, 32); a3 += __shfl_xor(a3, 32);
  if (sub == 0) {
    int o = 0;
    o = __builtin_amdgcn_cvt_pk_fp8_f32(a0, a1, o, false);
    o = __builtin_amdgcn_cvt_pk_fp8_f32(a2, a3, o, true);
    *(int*)(hs + (size_t)slice * SLSZ + (size_t)node * 32 + po) = o;
  }
}

// ============================================================================
// fp8 MFMA GEMM, 128x128 tile, BK=64 (64B/row), double-buffered.
// SLICED=1: A is in [8][NN][32B] slice layout. TIN=1: bn from raw sums.
// ============================================================================
template <int ACT, int TIN, int STATS, int SLICED>
__global__ __launch_bounds__(256, 2) void k_gemm8(
    const unsigned char* __restrict__ A, const unsigned char* __restrict__ BT,
    const float* __restrict__ bias, unsigned char* __restrict__ C, int M,
    const float* __restrict__ tsum, const float* __restrict__ tssq,
    const float* __restrict__ tg, const float* __restrict__ tbe,
    float* __restrict__ gsum, float* __restrict__ gssq) {
  __shared__ char smem[32768];
  __shared__ float lsc[256], lsh[256];
  __shared__ float lsum[128], lssq[128];
  int tid = threadIdx.x, lane = tid & 63, w = tid >> 6;
  if (TIN) {
    float mu = tsum[tid] / (float)M;
    float var = tssq[tid] / (float)M - mu * mu;
    float rs = rsqrtf(var + 1e-5f);
    float sc = tg[tid] * rs;
    lsc[tid] = sc; lsh[tid] = tbe[tid] - mu * sc;
  }
  if (STATS && tid < 128) { lsum[tid] = 0.f; lssq[tid] = 0.f; }
  int bm = blockIdx.x >> 1, bn = blockIdx.x & 1;
  int bm0 = bm * 128, bn0 = bn * 128;
  int wm = w >> 1, wn = w & 1;
  int lr = lane & 15, lg = lane >> 4;
  f32x4 acc[4][4] = {};
  __syncthreads();

  int4 stg[2];

#pragma unroll 1
  for (int it = 0; it < 4; ++it) {
    int b = it & 1;
    if (it == 0) {
      if (TIN) {
#pragma unroll
        for (int i = 0; i < 2; ++i) {
          int p = i * 256 + tid, unit = p >> 3, u = (p & 7) ^ (unit & 7);
          int srow = unit * 2 + (u >> 2), slot = u & 3;
          int grow = bm0 + srow; if (grow > M - 1) grow = M - 1;
          stg[i] = *(const int4*)(A + (size_t)grow * 256 + slot * 16);
        }
      } else {
#pragma unroll
        for (int q = 0; q < 2; ++q) {
          int wc = w * 2 + q;
          int p = wc * 64 + lane, unit = p >> 3, u = (p & 7) ^ (unit & 7);
          int srow = unit * 2 + (u >> 2), slot = u & 3;
          int grow = bm0 + srow; if (grow > M - 1) grow = M - 1;
          if (SLICED) {
            int kb = slot * 16;
            gload16(A + (size_t)(kb >> 5) * SLSZ + (size_t)grow * 32 + (kb & 31),
                    smem + wc * 1024);
          } else {
            gload16(A + (size_t)grow * 256 + slot * 16, smem + wc * 1024);
          }
        }
      }
#pragma unroll
      for (int q = 0; q < 2; ++q) {
        int wc = w * 2 + q;
        int p = wc * 64 + lane, unit = p >> 3, u = (p & 7) ^ (unit & 7);
        int srow = unit * 2 + (u >> 2), slot = u & 3;
        gload16(BT + (size_t)(bn0 + srow) * 256 + slot * 16, smem + 8192 + wc * 1024);
      }
      if (TIN) {
#pragma unroll
        for (int i = 0; i < 2; ++i) {
          int p = i * 256 + tid, unit = p >> 3, u = (p & 7) ^ (unit & 7);
          int slot = u & 3;
          int k0 = slot * 16;
          float f[16];
          up4(stg[i].x, f); up4(stg[i].y, f + 4); up4(stg[i].z, f + 8); up4(stg[i].w, f + 12);
#pragma unroll
          for (int jj = 0; jj < 16; ++jj) f[jj] = fmaxf(f[jj] * lsc[k0 + jj] + lsh[k0 + jj], 0.f);
          int w0 = 0, w1 = 0, w2 = 0, w3 = 0;
          w0 = __builtin_amdgcn_cvt_pk_fp8_f32(f[0], f[1], w0, false);
          w0 = __builtin_amdgcn_cvt_pk_fp8_f32(f[2], f[3], w0, true);
          w1 = __builtin_amdgcn_cvt_pk_fp8_f32(f[4], f[5], w1, false);
          w1 = __builtin_amdgcn_cvt_pk_fp8_f32(f[6], f[7], w1, true);
          w2 = __builtin_amdgcn_cvt_pk_fp8_f32(f[8], f[9], w2, false);
          w2 = __builtin_amdgcn_cvt_pk_fp8_f32(f[10], f[11], w2, true);
          w3 = __builtin_amdgcn_cvt_pk_fp8_f32(f[12], f[13], w3, false);
          w3 = __builtin_amdgcn_cvt_pk_fp8_f32(f[14], f[15], w3, true);
          *(int4*)(smem + p * 16) = make_int4(w0, w1, w2, w3);
        }
      }
      __syncthreads();
    }
    int ktn = (it + 1) * 64;
    if (it < 3) {
      char* nb = smem + (b ^ 1) * 16384;
      if (TIN) {
#pragma unroll
        for (int i = 0; i < 2; ++i) {
          int p = i * 256 + tid, unit = p >> 3, u = (p & 7) ^ (unit & 7);
          int srow = unit * 2 + (u >> 2), slot = u & 3;
          int grow = bm0 + srow; if (grow > M - 1) grow = M - 1;
          stg[i] = *(const int4*)(A + (size_t)grow * 256 + ktn + slot * 16);
        }
      } else {
#pragma unroll
        for (int q = 0; q < 2; ++q) {
          int wc = w * 2 + q;
          int p = wc * 64 + lane, unit = p >> 3, u = (p & 7) ^ (unit & 7);
          int srow = unit * 2 + (u >> 2), slot = u & 3;
          int grow = bm0 + srow; if (grow > M - 1) grow = M - 1;
          if (SLICED) {
            int kb = ktn + slot * 16;
            gload16(A + (size_t)(kb >> 5) * SLSZ + (size_t)grow * 32 + (kb & 31),
                    nb + wc * 1024);
          } else {
            gload16(A + (size_t)grow * 256 + ktn + slot * 16, nb + wc * 1024);
          }
        }
      }
#pragma unroll
      for (int q = 0; q < 2; ++q) {
        int wc = w * 2 + q;
        int p = wc * 64 + lane, unit = p >> 3, u = (p & 7) ^ (unit & 7);
        int srow = unit * 2 + (u >> 2), slot = u & 3;
        gload16(BT + (size_t)(bn0 + srow) * 256 + ktn + slot * 16, nb + 8192 + wc * 1024);
      }
    }
    const char* sa = smem + b * 16384;
    const char* sb = sa + 8192;
#pragma unroll
    for (int ks = 0; ks < 2; ++ks) {
      long af[4], bfr[4];
#pragma unroll
      for (int mi = 0; mi < 4; ++mi) {
        int row = wm * 64 + mi * 16 + lr;
        int unit = row >> 1;
        int u = ((row & 1) * 4 + ks * 2 + (lg >> 1)) ^ (unit & 7);
        af[mi] = *(const long*)(sa + unit * 128 + u * 16 + (lg & 1) * 8);
      }
#pragma unroll
      for (int ni = 0; ni < 4; ++ni) {
        int row = wn * 64 + ni * 16 + lr;
        int unit = row >> 1;
        int u = ((row & 1) * 4 + ks * 2 + (lg >> 1)) ^ (unit & 7);
        bfr[ni] = *(const long*)(sb + unit * 128 + u * 16 + (lg & 1) * 8);
      }
#pragma unroll
      for (int mi = 0; mi < 4; ++mi)
#pragma unroll
        for (int ni = 0; ni < 4; ++ni)
          acc[mi][ni] = __builtin_amdgcn_mfma_f32_16x16x32_fp8_fp8(af[mi], bfr[ni], acc[mi][ni], 0, 0, 0);
    }
    if (TIN && it < 3) {
      char* nb = smem + (b ^ 1) * 16384;
#pragma unroll
      for (int i = 0; i < 2; ++i) {
        int p = i * 256 + tid, unit = p >> 3, u = (p & 7) ^ (unit & 7);
        int slot = u & 3;
        int k0 = ktn + slot * 16;
        float f[16];
        up4(stg[i].x, f); up4(stg[i].y, f + 4); up4(stg[i].z, f + 8); up4(stg[i].w, f + 12);
#pragma unroll
        for (int jj = 0; jj < 16; ++jj) f[jj] = fmaxf(f[jj] * lsc[k0 + jj] + lsh[k0 + jj], 0.f);
        int w0 = 0, w1 = 0, w2 = 0, w3 = 0;
        w0 = __builtin_amdgcn_cvt_pk_fp8_f32(f[0], f[1], w0, false);
        w0 = __builtin_amdgcn_cvt_pk_fp8_f32(f[2], f[3], w0, true);
        w1 = __builtin_amdgcn_cvt_pk_fp8_f32(f[4], f[5], w1, false);
        w1 = __builtin_amdgcn_cvt_pk_fp8_f32(f[6], f[7], w1, true);
        w2 = __builtin_amdgcn_cvt_pk_fp8_f32(f[8], f[9], w2, false);
        w2 = __builtin_amdgcn_cvt_pk_fp8_f32(f[10], f[11], w2, true);
        w3 = __builtin_amdgcn_cvt_pk_fp8_f32(f[12], f[13], w3, false);
        w3 = __builtin_amdgcn_cvt_pk_fp8_f32(f[14], f[15], w3, true);
        *(int4*)(nb + p * 16) = make_int4(w0, w1, w2, w3);
      }
    }
    __syncthreads();
  }

  unsigned char* zs = (unsigned char*)smem;  // [128][144] fp8
#pragma unroll
  for (int ni = 0; ni < 4; ++ni) {
    int col = wn * 64 + ni * 16 + lr;
    float bv = bias[bn0 + col];
    float ps = 0.f, pq = 0.f;
#pragma unroll
    for (int mi = 0; mi < 4; ++mi) {
#pragma unroll
      for (int r = 0; r < 4; ++r) {
        int row = wm * 64 + mi * 16 + lg * 4 + r;
        float tv = acc[mi][ni][r] + bv;
        if (ACT == 1) tv = tv > 0.f ? tv : 0.01f * tv;  // lrelu(lrelu(t,0.1),0.1)
        if (STATS && (bm0 + row) < M) { ps += tv; pq += tv * tv; }
        zs[row * 144 + col] = f2fp8(tv);
      }
    }
    if (STATS) {
      ps += __shfl_xor(ps, 16); pq += __shfl_xor(pq, 16);
      ps += __shfl_xor(ps, 32); pq += __shfl_xor(pq, 32);
      if (lane < 16) {
        atomicAdd(&lsum[wn * 64 + ni * 16 + lane], ps);
        atomicAdd(&lssq[wn * 64 + ni * 16 + lane], pq);
      }
    }
  }
  __syncthreads();
  {
    int row = tid >> 1;
    int grow = bm0 + row;
    if (grow < M) {
#pragma unroll
      for (int i = 0; i < 4; ++i) {
        int cs = (tid & 1) * 64 + i * 16;
        int4 v = *(const int4*)(zs + row * 144 + cs);
        *(int4*)(C + (size_t)grow * 256 + bn0 + cs) = v;
      }
    }
  }
  if (STATS) {
    if (tid < 128) {
      atomicAdd(&gsum[bn0 + tid], lsum[tid]);
      atomicAdd(&gssq[bn0 + tid], lssq[tid]);
    }
  }
}

// ============================================================================
// head: bn4 scale/shift from raw sums; A' = bf16(x + 0.01*lrelu(bn4(V[fp8])));
// z = lrelu(A' @ Wl1 + bl1); out = z @ Wl3 + bl3 via 128x16 MFMA.
// ============================================================================
__global__ __launch_bounds__(256, 2) void k_head(const unsigned char* __restrict__ Vq,
                                                 const float* __restrict__ x,
                                                 const short* __restrict__ BT,
                                                 const float* __restrict__ bl1,
                                                 const short* __restrict__ wl3t,
                                                 const float* __restrict__ bl3,
                                                 const float* __restrict__ tsum,
                                                 const float* __restrict__ tssq,
                                                 const float* __restrict__ tg,
                                                 const float* __restrict__ tbe,
                                                 float* __restrict__ out, int M) {
  __shared__ char smem[65536];
  __shared__ float lsc[256], lsh[256];
  __shared__ short wl3s[2048];
  int tid = threadIdx.x;
  int lane = tid & 63, w = tid >> 6;
  {
    float mu = tsum[tid] / (float)M;
    float var = tssq[tid] / (float)M - mu * mu;
    float rs = rsqrtf(var + 1e-5f);
    float sc = tg[tid] * rs;
    lsc[tid] = sc; lsh[tid] = tbe[tid] - mu * sc;
  }
  {
    int p = w * 64 + lane;
    gload16(wl3t + (size_t)p * 8, (char*)wl3s + w * 1024);
  }
  int bm0 = blockIdx.x * 128;
  int wm = w >> 1, wn = w & 1;
  int lr = lane & 15, lg = lane >> 4;
  f32x4 acc[4][4] = {};
  __syncthreads();

  int2 stgv[4];
  float stgx[4][8];

#pragma unroll 1
  for (int it = 0; it < 4; ++it) {
    int b = it & 1;
    if (it == 0) {
#pragma unroll
      for (int i = 0; i < 4; ++i) {
        int p = tid + 256 * i, row = p >> 3, s = (p & 7) ^ (row & 7);
        int grow = bm0 + row; if (grow > M - 1) grow = M - 1;
        size_t base = (size_t)grow * 256 + s * 8;
        stgv[i] = *(const int2*)(Vq + base);
        *(float4*)&stgx[i][0] = *(const float4*)(x + base);
        *(float4*)&stgx[i][4] = *(const float4*)(x + base + 4);
      }
#pragma unroll
      for (int q = 0; q < 4; ++q) {
        int wc = w * 4 + q;
        int p = wc * 64 + lane, row = p >> 3, s = (p & 7) ^ (row & 7);
        gload16(BT + (size_t)row * 256 + s * 8, smem + 16384 + wc * 1024);
      }
#pragma unroll
      for (int i = 0; i < 4; ++i) {
        int p = tid + 256 * i, row = p >> 3, s = (p & 7) ^ (row & 7);
        int k0 = s * 8;
        float fv[8];
        up4(stgv[i].x, fv); up4(stgv[i].y, fv + 4);
        bf16x8 o;
#pragma unroll
        for (int jj = 0; jj < 8; ++jj) {
          float f = fv[jj] * lsc[k0 + jj] + lsh[k0 + jj];
          f = f > 0.f ? f : 0.1f * f;
          o[jj] = f2bf(stgx[i][jj] + 0.01f * f);
        }
        *(bf16x8*)(smem + p * 16) = o;
      }
      __syncthreads();
    }
    int ktn = (it + 1) * 64;
    if (it < 3) {
      char* nb = smem + (b ^ 1) * 32768;
#pragma unroll
      for (int i = 0; i < 4; ++i) {
        int p = tid + 256 * i, row = p >> 3, s = (p & 7) ^ (row & 7);
        int grow = bm0 + row; if (grow > M - 1) grow = M - 1;
        size_t base = (size_t)grow * 256 + ktn + s * 8;
        stgv[i] = *(const int2*)(Vq + base);
        *(float4*)&stgx[i][0] = *(const float4*)(x + base);
        *(float4*)&stgx[i][4] = *(const float4*)(x + base + 4);
      }
#pragma unroll
      for (int q = 0; q < 4; ++q) {
        int wc = w * 4 + q;
        int p = wc * 64 + lane, row = p >> 3, s = (p & 7) ^ (row & 7);
        gload16(BT + (size_t)row * 256 + ktn + s * 8, nb + 16384 + wc * 1024);
      }
    }
    const char* sa = smem + b * 32768;
    const char* sb = sa + 16384;
#pragma unroll
    for (int ks = 0; ks < 2; ++ks) {
      bf16x8 af[4], bfr[4];
#pragma unroll
      for (int mi = 0; mi < 4; ++mi) {
        int row = wm * 64 + mi * 16 + lr;
        int q = (lg + 4 * ks) ^ (row & 7);
        af[mi] = *(const bf16x8*)(sa + row * 128 + q * 16);
      }
#pragma unroll
      for (int ni = 0; ni < 4; ++ni) {
        int row = wn * 64 + ni * 16 + lr;
        int q = (lg + 4 * ks) ^ (row & 7);
        bfr[ni] = *(const bf16x8*)(sb + row * 128 + q * 16);
      }
#pragma unroll
      for (int mi = 0; mi < 4; ++mi)
#pragma unroll
        for (int ni = 0; ni < 4; ++ni)
          acc[mi][ni] = __builtin_amdgcn_mfma_f32_16x16x32_bf16(af[mi], bfr[ni], acc[mi][ni], 0, 0, 0);
    }
    if (it < 3) {
      char* nb = smem + (b ^ 1) * 32768;
#pragma unroll
      for (int i = 0; i < 4; ++i) {
        int p = tid + 256 * i, row = p >> 3, s = (p & 7) ^ (row & 7);
        int k0 = ktn + s * 8;
        float fv[8];
        up4(stgv[i].x, fv); up4(stgv[i].y, fv + 4);
        bf16x8 o;
#pragma unroll
        for (int jj = 0; jj < 8; ++jj) {
          float f = fv[jj] * lsc[k0 + jj] + lsh[k0 + jj];
          f = f > 0.f ? f : 0.1f * f;
          o[jj] = f2bf(stgx[i][jj] + 0.01f * f);
        }
        *(bf16x8*)(nb + p * 16) = o;
      }
    }
    __syncthreads();
  }

  short* zs = (short*)smem;  // [128][136] bf16
#pragma unroll
  for (int ni = 0; ni < 4; ++ni) {
    int col = wn * 64 + ni * 16 + lr;
    float bv = bl1[col];
#pragma unroll
    for (int mi = 0; mi < 4; ++mi) {
#pragma unroll
      for (int r = 0; r < 4; ++r) {
        int row = wm * 64 + mi * 16 + lg * 4 + r;
        float tv = acc[mi][ni][r] + bv;
        tv = tv > 0.f ? tv : 0.1f * tv;
        zs[row * 136 + col] = f2bf(tv);
      }
    }
  }
  __syncthreads();

  f32x4 acc2[2] = {};
#pragma unroll
  for (int kk = 0; kk < 4; ++kk) {
    bf16x8 bfr = *(const bf16x8*)((const char*)wl3s + lr * 256 + (kk * 4 + lg) * 16);
#pragma unroll
    for (int m = 0; m < 2; ++m) {
      int row = (w * 2 + m) * 16 + lr;
      bf16x8 af = *(const bf16x8*)((const char*)zs + row * 272 + (kk * 4 + lg) * 16);
      acc2[m] = __builtin_amdgcn_mfma_f32_16x16x32_bf16(af, bfr, acc2[m], 0, 0, 0);
    }
  }
  if (lr < 10) {
    float bv = bl3[lr];
#pragma unroll
    for (int m = 0; m < 2; ++m) {
#pragma unroll
      for (int r = 0; r < 4; ++r) {
        int row = (w * 2 + m) * 16 + lg * 4 + r;
        int grow = bm0 + row;
        if (grow < M) out[(size_t)grow * 10 + lr] = acc2[m][r] + bv;
      }
    }
  }
}

extern "C" void kernel_launch(void* const* d_in, const int* in_sizes, int n_in,
                              void* d_out, int out_size, void* d_ws, size_t ws_size,
                              hipStream_t stream) {
  const float* x   = (const float*)d_in[0];
  const int*   ew  = (const int*)d_in[1];
  const float* W1  = (const float*)d_in[2];
  const float* b1  = (const float*)d_in[3];
  const float* g1  = (const float*)d_in[4];
  const float* be1 = (const float*)d_in[5];
  const float* W2  = (const float*)d_in[6];
  const float* b2  = (const float*)d_in[7];
  const float* g4  = (const float*)d_in[8];
  const float* be4 = (const float*)d_in[9];
  const float* Wl1 = (const float*)d_in[10];
  const float* bl1 = (const float*)d_in[11];
  const float* Wl3 = (const float*)d_in[12];
  const float* bl3 = (const float*)d_in[13];
  float* out = (float*)d_out;

  char* ws = (char*)d_ws;
  const size_t OFF_OFF  = 0;          // (N+1) ints
  const size_t OFF_BASES= 400128;     // NBUCK+1 ints
  const size_t OFF_CNT  = 800256;     // CGRID x NBUCK ints (306KB)
  const size_t OFF_WL3T = 1106944;    // 16x128 bf16 (4KB)
  const size_t OFF_STATS= 1200384;    // 4x256 f32 (zeroed in k_detect)
  const size_t OFF_FLAG = 1208576;
  const size_t OFF_W1T  = 1209216;    // fp8 64KB
  const size_t OFF_W2T  = 1340288;    // fp8 64KB
  const size_t OFF_WL1T = 1471360;    // bf16 64KB
  const size_t OFF_CSR  = 1536896;    // NE ints (6.4MB)
  const size_t OFF_BUFA = 7936896;    // pairs (6.4MB) aliases; h0-sliced / h2
  const size_t OFF_BUFB = 59136896;   // xs-sliced aliases; h1 linear fp8
  if (ws_size < 110336896) return;

  int* off_  = (int*)(ws + OFF_OFF);
  int* bases_= (int*)(ws + OFF_BASES);
  int* cnt_  = (int*)(ws + OFF_CNT);
  float* sum1 = (float*)(ws + OFF_STATS);
  float* ssq1 = sum1 + 256;
  float* sum4 = sum1 + 512;
  float* ssq4 = sum1 + 768;
  int* flag_ = (int*)(ws + OFF_FLAG);
  unsigned char* W1T8 = (unsigned char*)(ws + OFF_W1T);
  unsigned char* W2T8 = (unsigned char*)(ws + OFF_W2T);
  short* Wl1T = (short*)(ws + OFF_WL1T);
  short* Wl3T = (short*)(ws + OFF_WL3T);
  int* csr_   = (int*)(ws + OFF_CSR);
  unsigned char* bufA = (unsigned char*)(ws + OFF_BUFA);
  unsigned char* bufB = (unsigned char*)(ws + OFF_BUFB);
  int* pairs_ = (int*)(ws + OFF_BUFA);  // alias: dead before k_agg4 writes bufA
  unsigned char* xs = bufB;             // sliced xq; dead before GEMM1 writes bufB

  k_detect<<<1, 256, 0, stream>>>(ew, flag_, sum1);
  k_cvtW<<<641, 256, 0, stream>>>(W1, W2, Wl1, Wl3, W1T8, W2T8, Wl1T, Wl3T);
  k_cvtX<<<12500, 256, 0, stream>>>(x, xs);
  k_count<<<CGRID, 1024, 0, stream>>>(ew, flag_, cnt_);
  k_colscan<<<1, 1024, 0, stream>>>(cnt_, bases_, off_);
  k_scatter<<<CGRID, 1024, 0, stream>>>(ew, flag_, cnt_, pairs_);
  k_bsort<<<NBUCK, 256, 0, stream>>>(pairs_, bases_, off_, csr_);
  k_agg4<<<200000, 256, 0, stream>>>(xs, off_, csr_, bufA);  // bufA = h0 sliced
  k_gemm8<0, 0, 1, 1><<<1564, 256, 0, stream>>>(bufA, W1T8, b1, bufB, NN,
                                                nullptr, nullptr, nullptr, nullptr,
                                                sum1, ssq1);
  k_gemm8<1, 1, 1, 0><<<1564, 256, 0, stream>>>(bufB, W2T8, b2, bufA, NN,
                                                sum1, ssq1, g1, be1, sum4, ssq4);
  k_head<<<782, 256, 0, stream>>>(bufA, x, Wl1T, bl1, Wl3T, bl3,
                                  sum4, ssq4, g4, be4, out, NN);
}

// Round 13
// 257.638 us; speedup vs baseline: 1.5195x; 1.5195x over previous
//
#include <hip/hip_runtime.h>

constexpr int NN = 100000;   // nodes
constexpr int NE = 1600000;  // edges
constexpr int NBUCK = 782;   // ceil(NN/128)
constexpr int CGRID = 98;    // count/scatter blocks (98*16384 >= NE)

typedef __attribute__((ext_vector_type(4))) float  f32x4;
typedef __attribute__((ext_vector_type(2))) float  f32x2;
typedef __attribute__((ext_vector_type(8))) short  bf16x8;

__device__ __forceinline__ float bf2f(unsigned short u) {
  union { unsigned int i; float f; } c;
  c.i = ((unsigned int)u) << 16;
  return c.f;
}
__device__ __forceinline__ short f2bf(float f) {
  union { float f; unsigned int i; } c; c.f = f;
  unsigned int i = c.i + 0x7fffu + ((c.i >> 16) & 1u);
  return (short)(i >> 16);
}
__device__ __forceinline__ unsigned char f2fp8(float f) {
  int w = __builtin_amdgcn_cvt_pk_fp8_f32(f, 0.f, 0, false);
  return (unsigned char)(w & 0xff);
}
__device__ __forceinline__ void up4(int wv, float* f) {
  f32x2 a = __builtin_amdgcn_cvt_pk_f32_fp8(wv, false);
  f32x2 b = __builtin_amdgcn_cvt_pk_f32_fp8(wv, true);
  f[0] = a[0]; f[1] = a[1]; f[2] = b[0]; f[3] = b[1];
}

// async global->LDS, 16B per lane; LDS dest is wave-uniform base + lane*16
__device__ __forceinline__ void gload16(const void* g, void* l) {
  __builtin_amdgcn_global_load_lds(
      (const __attribute__((address_space(1))) unsigned int*)g,
      (__attribute__((address_space(3))) unsigned int*)l, 16, 0, 0);
}

// ---- edge dtype detection + stats zeroing ----
__global__ void k_detect(const int* __restrict__ ew, int* __restrict__ flag,
                         float* __restrict__ zst) {
  __shared__ int bad;
  if (threadIdx.x == 0) bad = 0;
  for (int i = threadIdx.x; i < 1024; i += 256) zst[i] = 0.f;
  __syncthreads();
  int nz = 0;
  for (int i = threadIdx.x; i < 2048; i += 256) nz |= ew[2 * i + 1];
  if (nz) atomicOr(&bad, 1);
  __syncthreads();
  if (threadIdx.x == 0) *flag = (bad == 0) ? 1 : 0;
}

// ---- weights: W1,W2 -> fp8 transposed; Wl1 -> bf16 T; Wl3 -> bf16 [16][128] ----
__global__ void k_cvtW(const float* __restrict__ W1, const float* __restrict__ W2,
                       const float* __restrict__ Wl1, const float* __restrict__ Wl3,
                       unsigned char* __restrict__ W1T8, unsigned char* __restrict__ W2T8,
                       short* __restrict__ Wl1T, short* __restrict__ Wl3T) {
  int b = blockIdx.x, t = threadIdx.x;
  if (b < 256)       W1T8[b * 256 + t]       = f2fp8(W1[t * 256 + b]);
  else if (b < 512){ int n = b - 256; W2T8[n * 256 + t] = f2fp8(W2[t * 256 + n]); }
  else if (b < 640){ int n = b - 512; Wl1T[n * 256 + t] = f2bf(Wl1[t * 128 + n]); }
  else {
    if (t < 128) {
#pragma unroll
      for (int c = 0; c < 16; ++c)
        Wl3T[c * 128 + t] = (c < 10) ? f2bf(Wl3[t * 10 + c]) : (short)0;
    }
  }
}

// ---- x (f32) -> fp8 gather copy (linear [NN][256B]) ----
__global__ void k_cvtX(const float* __restrict__ x, void* __restrict__ xq) {
  int c = blockIdx.x * 256 + threadIdx.x;  // 3.2M chunks of 8, grid exact
  float4 a = ((const float4*)x)[2 * (size_t)c];
  float4 b = ((const float4*)x)[2 * (size_t)c + 1];
  int p0 = 0, p1 = 0;
  p0 = __builtin_amdgcn_cvt_pk_fp8_f32(a.x, a.y, p0, false);
  p0 = __builtin_amdgcn_cvt_pk_fp8_f32(a.z, a.w, p0, true);
  p1 = __builtin_amdgcn_cvt_pk_fp8_f32(b.x, b.y, p1, false);
  p1 = __builtin_amdgcn_cvt_pk_fp8_f32(b.z, b.w, p1, true);
  ((int2*)xq)[c] = make_int2(p0, p1);
}

// ---- pass 1: per-block bucket histogram (no global atomics) ----
__global__ __launch_bounds__(1024) void k_count(const int* __restrict__ ew,
                                                const int* __restrict__ flag,
                                                int* __restrict__ cntmat) {
  __shared__ int lcnt[NBUCK];
  int m64 = *flag;
  int t = threadIdx.x;
  for (int i = t; i < NBUCK; i += 1024) lcnt[i] = 0;
  __syncthreads();
  int base = blockIdx.x * 16384;
#pragma unroll
  for (int u = 0; u < 16; u++) {
    int e = base + u * 1024 + t;
    if (e < NE) {
      int d = m64 ? ew[2 * (NE + e)] : ew[NE + e];
      atomicAdd(&lcnt[d >> 7], 1);
    }
  }
  __syncthreads();
  for (int i = t; i < NBUCK; i += 1024) cntmat[blockIdx.x * NBUCK + i] = lcnt[i];
}

// ---- pass 2a: per-bucket scan across the 98 blocks (one wave per bucket).
// Round-8 UB fixed: bucket total computed CONVERGENTLY (all lanes run the
// shuffles, before any branch) and read from lane 63 (zero-padded, so the
// inclusive scan is constant past g=97). ----
__global__ __launch_bounds__(256) void k_cscan(int* __restrict__ cntmat,
                                               int* __restrict__ tot) {
  int wid = (blockIdx.x * 256 + threadIdx.x) >> 6;  // bucket
  int lane = threadIdx.x & 63;
  if (wid >= NBUCK) return;   // whole-wave uniform exit (wid is per-wave)
  int v0 = (lane < CGRID) ? cntmat[lane * NBUCK + wid] : 0;
  int v1 = (lane + 64 < CGRID) ? cntmat[(lane + 64) * NBUCK + wid] : 0;
  int s0 = v0;
#pragma unroll
  for (int o = 1; o < 64; o <<= 1) { int u = __shfl_up(s0, o); if (lane >= o) s0 += u; }
  int s1 = v1;
#pragma unroll
  for (int o = 1; o < 64; o <<= 1) { int u = __shfl_up(s1, o); if (lane >= o) s1 += u; }
  int t0 = __shfl(s0, 63);       // total of g=0..63   (convergent)
  int t1 = __shfl(s1, 63);       // total of g=64..97  (convergent, zero-padded)
  if (lane < CGRID) cntmat[lane * NBUCK + wid] = s0 - v0;            // exclusive
  if (lane + 64 < CGRID) cntmat[(lane + 64) * NBUCK + wid] = t0 + s1 - v1;
  if (lane == 0) tot[wid] = t0 + t1;
}

// ---- pass 2b: scan bucket totals -> bases ----
__global__ __launch_bounds__(1024) void k_bscan(const int* __restrict__ tot,
                                                int* __restrict__ bases,
                                                int* __restrict__ off_) {
  __shared__ int s[1024];
  int t = threadIdx.x;
  int v = (t < NBUCK) ? tot[t] : 0;
  s[t] = v; __syncthreads();
  for (int o = 1; o < 1024; o <<= 1) {
    int u = (t >= o) ? s[t - o] : 0;
    __syncthreads();
    s[t] += u;
    __syncthreads();
  }
  if (t < NBUCK) bases[t] = s[t] - v;  // exclusive
  if (t == 0) { bases[NBUCK] = NE; off_[NN] = NE; }
}

// ---- pass 3: dense bucketed scatter of packed (src | ld<<17) ----
__global__ __launch_bounds__(1024) void k_scatter(const int* __restrict__ ew,
                                                  const int* __restrict__ flag,
                                                  const int* __restrict__ cntmat,
                                                  const int* __restrict__ bases,
                                                  int* __restrict__ pairs) {
  __shared__ int lcur[NBUCK];
  int m64 = *flag;
  int t = threadIdx.x;
  for (int i = t; i < NBUCK; i += 1024)
    lcur[i] = bases[i] + cntmat[blockIdx.x * NBUCK + i];
  __syncthreads();
  int base = blockIdx.x * 16384;
#pragma unroll
  for (int u = 0; u < 16; u++) {
    int e = base + u * 1024 + t;
    if (e < NE) {
      int d = m64 ? ew[2 * (NE + e)] : ew[NE + e];
      int s = m64 ? ew[2 * e] : ew[e];
      int slot = atomicAdd(&lcur[d >> 7], 1);
      pairs[slot] = s | ((d & 127) << 17);
    }
  }
}

// ---- pass 4: per-bucket counting sort in LDS -> off_ + csr ----
__global__ __launch_bounds__(256) void k_bsort(const int* __restrict__ pairs,
                                               const int* __restrict__ bases,
                                               int* __restrict__ off_,
                                               int* __restrict__ csr) {
  __shared__ int lcnt[128], lofs[128], lcur[128];
  int b = blockIdx.x, t = threadIdx.x;
  int s0 = bases[b], s1 = bases[b + 1];
  if (t < 128) lcnt[t] = 0;
  __syncthreads();
  for (int j = s0 + t; j < s1; j += 256) atomicAdd(&lcnt[(pairs[j] >> 17) & 127], 1);
  __syncthreads();
  int v = (t < 128) ? lcnt[t] : 0;
  if (t < 128) lofs[t] = v;
  __syncthreads();
  for (int o = 1; o < 128; o <<= 1) {
    int u = (t >= o && t < 128) ? lofs[t - o] : 0;
    __syncthreads();
    if (t < 128) lofs[t] += u;
    __syncthreads();
  }
  if (t < 128) {
    int ex = lofs[t] - v;  // exclusive
    lcur[t] = ex;
    int node = b * 128 + t;
    if (node < NN) off_[node] = s0 + ex;
  }
  __syncthreads();
  for (int j = s0 + t; j < s1; j += 256) {
    int p = pairs[j];
    int slot = atomicAdd(&lcur[(p >> 17) & 127], 1);
    csr[s0 + slot] = p & 0x1FFFF;
  }
}

// one WAVE per node, lane owns 4 columns; fp8 in, fp8 out (round-7/10 proven)
__global__ __launch_bounds__(256) void k_agg2(const void* __restrict__ xq,
                                              const int* __restrict__ off_,
                                              const int* __restrict__ csr,
                                              unsigned char* __restrict__ h0) {
  int node = blockIdx.x * 4 + (threadIdx.x >> 6);  // grid 25000 exact
  int lane = threadIdx.x & 63;
  const unsigned char* xb = (const unsigned char*)xq;
  size_t boff = (size_t)lane * 4;  // byte offset within 256B row
  int s0 = off_[node], s1 = off_[node + 1];
  int sw = *(const int*)(xb + (size_t)node * 256 + boff);
  f32x2 slo = __builtin_amdgcn_cvt_pk_f32_fp8(sw, false);
  f32x2 shi = __builtin_amdgcn_cvt_pk_f32_fp8(sw, true);
  float a0 = slo[0], a1 = slo[1], a2 = shi[0], a3 = shi[1];
  int j = s0;
  while (j + 8 <= s1) {
    int idx[8];
#pragma unroll
    for (int u = 0; u < 8; u++) idx[u] = csr[j + u];
    int w[8];
#pragma unroll
    for (int u = 0; u < 8; u++) w[u] = *(const int*)(xb + (size_t)idx[u] * 256 + boff);
#pragma unroll
    for (int u = 0; u < 8; u++) {
      f32x2 lo = __builtin_amdgcn_cvt_pk_f32_fp8(w[u], false);
      f32x2 hi = __builtin_amdgcn_cvt_pk_f32_fp8(w[u], true);
      a0 += lo[0]; a1 += lo[1]; a2 += hi[0]; a3 += hi[1];
    }
    j += 8;
  }
  if (j + 4 <= s1) {
    int idx[4];
#pragma unroll
    for (int u = 0; u < 4; u++) idx[u] = csr[j + u];
    int w[4];
#pragma unroll
    for (int u = 0; u < 4; u++) w[u] = *(const int*)(xb + (size_t)idx[u] * 256 + boff);
#pragma unroll
    for (int u = 0; u < 4; u++) {
      f32x2 lo = __builtin_amdgcn_cvt_pk_f32_fp8(w[u], false);
      f32x2 hi = __builtin_amdgcn_cvt_pk_f32_fp8(w[u], true);
      a0 += lo[0]; a1 += lo[1]; a2 += hi[0]; a3 += hi[1];
    }
    j += 4;
  }
  for (; j < s1; j++) {
    int s = csr[j];
    int w = *(const int*)(xb + (size_t)s * 256 + boff);
    f32x2 lo = __builtin_amdgcn_cvt_pk_f32_fp8(w, false);
    f32x2 hi = __builtin_amdgcn_cvt_pk_f32_fp8(w, true);
    a0 += lo[0]; a1 += lo[1]; a2 += hi[0]; a3 += hi[1];
  }
  int o = 0;
  o = __builtin_amdgcn_cvt_pk_fp8_f32(a0, a1, o, false);
  o = __builtin_amdgcn_cvt_pk_fp8_f32(a2, a3, o, true);
  ((int*)h0)[(size_t)node * 64 + lane] = o;
}

// ============================================================================
// fp8 MFMA GEMM, 128x128 tile, BK=64 (64B/row), double-buffered.
// TIN=1: bn scale/shift from raw sums in preamble; A'=fp8(relu(bn(A))) during
// reg staging (issue-early / write-late). STATS: col sum/ssq of output.
// ============================================================================
template <int ACT, int TIN, int STATS>
__global__ __launch_bounds__(256, 2) void k_gemm8(
    const unsigned char* __restrict__ A, const unsigned char* __restrict__ BT,
    const float* __restrict__ bias, unsigned char* __restrict__ C, int M,
    const float* __restrict__ tsum, const float* __restrict__ tssq,
    const float* __restrict__ tg, const float* __restrict__ tbe,
    float* __restrict__ gsum, float* __restrict__ gssq) {
  __shared__ char smem[32768];
  __shared__ float lsc[256], lsh[256];
  __shared__ float lsum[128], lssq[128];
  int tid = threadIdx.x, lane = tid & 63, w = tid >> 6;
  if (TIN) {
    float mu = tsum[tid] / (float)M;
    float var = tssq[tid] / (float)M - mu * mu;
    float rs = rsqrtf(var + 1e-5f);
    float sc = tg[tid] * rs;
    lsc[tid] = sc; lsh[tid] = tbe[tid] - mu * sc;
  }
  if (STATS && tid < 128) { lsum[tid] = 0.f; lssq[tid] = 0.f; }
  int bm = blockIdx.x >> 1, bn = blockIdx.x & 1;
  int bm0 = bm * 128, bn0 = bn * 128;
  int wm = w >> 1, wn = w & 1;
  int lr = lane & 15, lg = lane >> 4;
  f32x4 acc[4][4] = {};
  __syncthreads();

  int4 stg[2];

#pragma unroll 1
  for (int it = 0; it < 4; ++it) {
    int b = it & 1;
    if (it == 0) {
      if (TIN) {
#pragma unroll
        for (int i = 0; i < 2; ++i) {
          int p = i * 256 + tid, unit = p >> 3, u = (p & 7) ^ (unit & 7);
          int srow = unit * 2 + (u >> 2), slot = u & 3;
          int grow = bm0 + srow; if (grow > M - 1) grow = M - 1;
          stg[i] = *(const int4*)(A + (size_t)grow * 256 + slot * 16);
        }
      } else {
#pragma unroll
        for (int q = 0; q < 2; ++q) {
          int wc = w * 2 + q;
          int p = wc * 64 + lane, unit = p >> 3, u = (p & 7) ^ (unit & 7);
          int srow = unit * 2 + (u >> 2), slot = u & 3;
          int grow = bm0 + srow; if (grow > M - 1) grow = M - 1;
          gload16(A + (size_t)grow * 256 + slot * 16, smem + wc * 1024);
        }
      }
#pragma unroll
      for (int q = 0; q < 2; ++q) {
        int wc = w * 2 + q;
        int p = wc * 64 + lane, unit = p >> 3, u = (p & 7) ^ (unit & 7);
        int srow = unit * 2 + (u >> 2), slot = u & 3;
        gload16(BT + (size_t)(bn0 + srow) * 256 + slot * 16, smem + 8192 + wc * 1024);
      }
      if (TIN) {
#pragma unroll
        for (int i = 0; i < 2; ++i) {
          int p = i * 256 + tid, unit = p >> 3, u = (p & 7) ^ (unit & 7);
          int slot = u & 3;
          int k0 = slot * 16;
          float f[16];
          up4(stg[i].x, f); up4(stg[i].y, f + 4); up4(stg[i].z, f + 8); up4(stg[i].w, f + 12);
#pragma unroll
          for (int jj = 0; jj < 16; ++jj) f[jj] = fmaxf(f[jj] * lsc[k0 + jj] + lsh[k0 + jj], 0.f);
          int w0 = 0, w1 = 0, w2 = 0, w3 = 0;
          w0 = __builtin_amdgcn_cvt_pk_fp8_f32(f[0], f[1], w0, false);
          w0 = __builtin_amdgcn_cvt_pk_fp8_f32(f[2], f[3], w0, true);
          w1 = __builtin_amdgcn_cvt_pk_fp8_f32(f[4], f[5], w1, false);
          w1 = __builtin_amdgcn_cvt_pk_fp8_f32(f[6], f[7], w1, true);
          w2 = __builtin_amdgcn_cvt_pk_fp8_f32(f[8], f[9], w2, false);
          w2 = __builtin_amdgcn_cvt_pk_fp8_f32(f[10], f[11], w2, true);
          w3 = __builtin_amdgcn_cvt_pk_fp8_f32(f[12], f[13], w3, false);
          w3 = __builtin_amdgcn_cvt_pk_fp8_f32(f[14], f[15], w3, true);
          *(int4*)(smem + p * 16) = make_int4(w0, w1, w2, w3);
        }
      }
      __syncthreads();
    }
    int ktn = (it + 1) * 64;
    if (it < 3) {
      char* nb = smem + (b ^ 1) * 16384;
      if (TIN) {
#pragma unroll
        for (int i = 0; i < 2; ++i) {
          int p = i * 256 + tid, unit = p >> 3, u = (p & 7) ^ (unit & 7);
          int srow = unit * 2 + (u >> 2), slot = u & 3;
          int grow = bm0 + srow; if (grow > M - 1) grow = M - 1;
          stg[i] = *(const int4*)(A + (size_t)grow * 256 + ktn + slot * 16);
        }
      } else {
#pragma unroll
        for (int q = 0; q < 2; ++q) {
          int wc = w * 2 + q;
          int p = wc * 64 + lane, unit = p >> 3, u = (p & 7) ^ (unit & 7);
          int srow = unit * 2 + (u >> 2), slot = u & 3;
          int grow = bm0 + srow; if (grow > M - 1) grow = M - 1;
          gload16(A + (size_t)grow * 256 + ktn + slot * 16, nb + wc * 1024);
        }
      }
#pragma unroll
      for (int q = 0; q < 2; ++q) {
        int wc = w * 2 + q;
        int p = wc * 64 + lane, unit = p >> 3, u = (p & 7) ^ (unit & 7);
        int srow = unit * 2 + (u >> 2), slot = u & 3;
        gload16(BT + (size_t)(bn0 + srow) * 256 + ktn + slot * 16, nb + 8192 + wc * 1024);
      }
    }
    const char* sa = smem + b * 16384;
    const char* sb = sa + 8192;
#pragma unroll
    for (int ks = 0; ks < 2; ++ks) {
      long af[4], bfr[4];
#pragma unroll
      for (int mi = 0; mi < 4; ++mi) {
        int row = wm * 64 + mi * 16 + lr;
        int unit = row >> 1;
        int u = ((row & 1) * 4 + ks * 2 + (lg >> 1)) ^ (unit & 7);
        af[mi] = *(const long*)(sa + unit * 128 + u * 16 + (lg & 1) * 8);
      }
#pragma unroll
      for (int ni = 0; ni < 4; ++ni) {
        int row = wn * 64 + ni * 16 + lr;
        int unit = row >> 1;
        int u = ((row & 1) * 4 + ks * 2 + (lg >> 1)) ^ (unit & 7);
        bfr[ni] = *(const long*)(sb + unit * 128 + u * 16 + (lg & 1) * 8);
      }
#pragma unroll
      for (int mi = 0; mi < 4; ++mi)
#pragma unroll
        for (int ni = 0; ni < 4; ++ni)
          acc[mi][ni] = __builtin_amdgcn_mfma_f32_16x16x32_fp8_fp8(af[mi], bfr[ni], acc[mi][ni], 0, 0, 0);
    }
    if (TIN && it < 3) {
      char* nb = smem + (b ^ 1) * 16384;
#pragma unroll
      for (int i = 0; i < 2; ++i) {
        int p = i * 256 + tid, unit = p >> 3, u = (p & 7) ^ (unit & 7);
        int slot = u & 3;
        int k0 = ktn + slot * 16;
        float f[16];
        up4(stg[i].x, f); up4(stg[i].y, f + 4); up4(stg[i].z, f + 8); up4(stg[i].w, f + 12);
#pragma unroll
        for (int jj = 0; jj < 16; ++jj) f[jj] = fmaxf(f[jj] * lsc[k0 + jj] + lsh[k0 + jj], 0.f);
        int w0 = 0, w1 = 0, w2 = 0, w3 = 0;
        w0 = __builtin_amdgcn_cvt_pk_fp8_f32(f[0], f[1], w0, false);
        w0 = __builtin_amdgcn_cvt_pk_fp8_f32(f[2], f[3], w0, true);
        w1 = __builtin_amdgcn_cvt_pk_fp8_f32(f[4], f[5], w1, false);
        w1 = __builtin_amdgcn_cvt_pk_fp8_f32(f[6], f[7], w1, true);
        w2 = __builtin_amdgcn_cvt_pk_fp8_f32(f[8], f[9], w2, false);
        w2 = __builtin_amdgcn_cvt_pk_fp8_f32(f[10], f[11], w2, true);
        w3 = __builtin_amdgcn_cvt_pk_fp8_f32(f[12], f[13], w3, false);
        w3 = __builtin_amdgcn_cvt_pk_fp8_f32(f[14], f[15], w3, true);
        *(int4*)(nb + p * 16) = make_int4(w0, w1, w2, w3);
      }
    }
    __syncthreads();
  }

  unsigned char* zs = (unsigned char*)smem;  // [128][144] fp8
#pragma unroll
  for (int ni = 0; ni < 4; ++ni) {
    int col = wn * 64 + ni * 16 + lr;
    float bv = bias[bn0 + col];
    float ps = 0.f, pq = 0.f;
#pragma unroll
    for (int mi = 0; mi < 4; ++mi) {
#pragma unroll
      for (int r = 0; r < 4; ++r) {
        int row = wm * 64 + mi * 16 + lg * 4 + r;
        float tv = acc[mi][ni][r] + bv;
        if (ACT == 1) tv = tv > 0.f ? tv : 0.01f * tv;  // lrelu(lrelu(t,0.1),0.1)
        if (STATS && (bm0 + row) < M) { ps += tv; pq += tv * tv; }
        zs[row * 144 + col] = f2fp8(tv);
      }
    }
    if (STATS) {
      ps += __shfl_xor(ps, 16); pq += __shfl_xor(pq, 16);
      ps += __shfl_xor(ps, 32); pq += __shfl_xor(pq, 32);
      if (lane < 16) {
        atomicAdd(&lsum[wn * 64 + ni * 16 + lane], ps);
        atomicAdd(&lssq[wn * 64 + ni * 16 + lane], pq);
      }
    }
  }
  __syncthreads();
  {
    int row = tid >> 1;
    int grow = bm0 + row;
    if (grow < M) {
#pragma unroll
      for (int i = 0; i < 4; ++i) {
        int cs = (tid & 1) * 64 + i * 16;
        int4 v = *(const int4*)(zs + row * 144 + cs);
        *(int4*)(C + (size_t)grow * 256 + bn0 + cs) = v;
      }
    }
  }
  if (STATS) {
    if (tid < 128) {
      atomicAdd(&gsum[bn0 + tid], lsum[tid]);
      atomicAdd(&gssq[bn0 + tid], lssq[tid]);
    }
  }
}

// ============================================================================
// head: bn4 scale/shift from raw sums; A' = bf16(x + 0.01*lrelu(bn4(V[fp8])));
// z = lrelu(A' @ Wl1 + bl1); out = z @ Wl3 + bl3 via 128x16 MFMA.
// ============================================================================
__global__ __launch_bounds__(256, 2) void k_head(const unsigned char* __restrict__ Vq,
                                                 const float* __restrict__ x,
                                                 const short* __restrict__ BT,
                                                 const float* __restrict__ bl1,
                                                 const short* __restrict__ wl3t,
                                                 const float* __restrict__ bl3,
                                                 const float* __restrict__ tsum,
                                                 const float* __restrict__ tssq,
                                                 const float* __restrict__ tg,
                                                 const float* __restrict__ tbe,
                                                 float* __restrict__ out, int M) {
  __shared__ char smem[65536];
  __shared__ float lsc[256], lsh[256];
  __shared__ short wl3s[2048];
  int tid = threadIdx.x;
  int lane = tid & 63, w = tid >> 6;
  {
    float mu = tsum[tid] / (float)M;
    float var = tssq[tid] / (float)M - mu * mu;
    float rs = rsqrtf(var + 1e-5f);
    float sc = tg[tid] * rs;
    lsc[tid] = sc; lsh[tid] = tbe[tid] - mu * sc;
  }
  {
    int p = w * 64 + lane;
    gload16(wl3t + (size_t)p * 8, (char*)wl3s + w * 1024);
  }
  int bm0 = blockIdx.x * 128;
  int wm = w >> 1, wn = w & 1;
  int lr = lane & 15, lg = lane >> 4;
  f32x4 acc[4][4] = {};
  __syncthreads();

  int2 stgv[4];
  float stgx[4][8];

#pragma unroll 1
  for (int it = 0; it < 4; ++it) {
    int b = it & 1;
    if (it == 0) {
#pragma unroll
      for (int i = 0; i < 4; ++i) {
        int p = tid + 256 * i, row = p >> 3, s = (p & 7) ^ (row & 7);
        int grow = bm0 + row; if (grow > M - 1) grow = M - 1;
        size_t base = (size_t)grow * 256 + s * 8;
        stgv[i] = *(const int2*)(Vq + base);
        *(float4*)&stgx[i][0] = *(const float4*)(x + base);
        *(float4*)&stgx[i][4] = *(const float4*)(x + base + 4);
      }
#pragma unroll
      for (int q = 0; q < 4; ++q) {
        int wc = w * 4 + q;
        int p = wc * 64 + lane, row = p >> 3, s = (p & 7) ^ (row & 7);
        gload16(BT + (size_t)row * 256 + s * 8, smem + 16384 + wc * 1024);
      }
#pragma unroll
      for (int i = 0; i < 4; ++i) {
        int p = tid + 256 * i, row = p >> 3, s = (p & 7) ^ (row & 7);
        int k0 = s * 8;
        float fv[8];
        up4(stgv[i].x, fv); up4(stgv[i].y, fv + 4);
        bf16x8 o;
#pragma unroll
        for (int jj = 0; jj < 8; ++jj) {
          float f = fv[jj] * lsc[k0 + jj] + lsh[k0 + jj];
          f = f > 0.f ? f : 0.1f * f;
          o[jj] = f2bf(stgx[i][jj] + 0.01f * f);
        }
        *(bf16x8*)(smem + p * 16) = o;
      }
      __syncthreads();
    }
    int ktn = (it + 1) * 64;
    if (it < 3) {
      char* nb = smem + (b ^ 1) * 32768;
#pragma unroll
      for (int i = 0; i < 4; ++i) {
        int p = tid + 256 * i, row = p >> 3, s = (p & 7) ^ (row & 7);
        int grow = bm0 + row; if (grow > M - 1) grow = M - 1;
        size_t base = (size_t)grow * 256 + ktn + s * 8;
        stgv[i] = *(const int2*)(Vq + base);
        *(float4*)&stgx[i][0] = *(const float4*)(x + base);
        *(float4*)&stgx[i][4] = *(const float4*)(x + base + 4);
      }
#pragma unroll
      for (int q = 0; q < 4; ++q) {
        int wc = w * 4 + q;
        int p = wc * 64 + lane, row = p >> 3, s = (p & 7) ^ (row & 7);
        gload16(BT + (size_t)row * 256 + ktn + s * 8, nb + 16384 + wc * 1024);
      }
    }
    const char* sa = smem + b * 32768;
    const char* sb = sa + 16384;
#pragma unroll
    for (int ks = 0; ks < 2; ++ks) {
      bf16x8 af[4], bfr[4];
#pragma unroll
      for (int mi = 0; mi < 4; ++mi) {
        int row = wm * 64 + mi * 16 + lr;
        int q = (lg + 4 * ks) ^ (row & 7);
        af[mi] = *(const bf16x8*)(sa + row * 128 + q * 16);
      }
#pragma unroll
      for (int ni = 0; ni < 4; ++ni) {
        int row = wn * 64 + ni * 16 + lr;
        int q = (lg + 4 * ks) ^ (row & 7);
        bfr[ni] = *(const bf16x8*)(sb + row * 128 + q * 16);
      }
#pragma unroll
      for (int mi = 0; mi < 4; ++mi)
#pragma unroll
        for (int ni = 0; ni < 4; ++ni)
          acc[mi][ni] = __builtin_amdgcn_mfma_f32_16x16x32_bf16(af[mi], bfr[ni], acc[mi][ni], 0, 0, 0);
    }
    if (it < 3) {
      char* nb = smem + (b ^ 1) * 32768;
#pragma unroll
      for (int i = 0; i < 4; ++i) {
        int p = tid + 256 * i, row = p >> 3, s = (p & 7) ^ (row & 7);
        int k0 = ktn + s * 8;
        float fv[8];
        up4(stgv[i].x, fv); up4(stgv[i].y, fv + 4);
        bf16x8 o;
#pragma unroll
        for (int jj = 0; jj < 8; ++jj) {
          float f = fv[jj] * lsc[k0 + jj] + lsh[k0 + jj];
          f = f > 0.f ? f : 0.1f * f;
          o[jj] = f2bf(stgx[i][jj] + 0.01f * f);
        }
        *(bf16x8*)(nb + p * 16) = o;
      }
    }
    __syncthreads();
  }

  short* zs = (short*)smem;  // [128][136] bf16
#pragma unroll
  for (int ni = 0; ni < 4; ++ni) {
    int col = wn * 64 + ni * 16 + lr;
    float bv = bl1[col];
#pragma unroll
    for (int mi = 0; mi < 4; ++mi) {
#pragma unroll
      for (int r = 0; r < 4; ++r) {
        int row = wm * 64 + mi * 16 + lg * 4 + r;
        float tv = acc[mi][ni][r] + bv;
        tv = tv > 0.f ? tv : 0.1f * tv;
        zs[row * 136 + col] = f2bf(tv);
      }
    }
  }
  __syncthreads();

  f32x4 acc2[2] = {};
#pragma unroll
  for (int kk = 0; kk < 4; ++kk) {
    bf16x8 bfr = *(const bf16x8*)((const char*)wl3s + lr * 256 + (kk * 4 + lg) * 16);
#pragma unroll
    for (int m = 0; m < 2; ++m) {
      int row = (w * 2 + m) * 16 + lr;
      bf16x8 af = *(const bf16x8*)((const char*)zs + row * 272 + (kk * 4 + lg) * 16);
      acc2[m] = __builtin_amdgcn_mfma_f32_16x16x32_bf16(af, bfr, acc2[m], 0, 0, 0);
    }
  }
  if (lr < 10) {
    float bv = bl3[lr];
#pragma unroll
    for (int m = 0; m < 2; ++m) {
#pragma unroll
      for (int r = 0; r < 4; ++r) {
        int row = (w * 2 + m) * 16 + lg * 4 + r;
        int grow = bm0 + row;
        if (grow < M) out[(size_t)grow * 10 + lr] = acc2[m][r] + bv;
      }
    }
  }
}

extern "C" void kernel_launch(void* const* d_in, const int* in_sizes, int n_in,
                              void* d_out, int out_size, void* d_ws, size_t ws_size,
                              hipStream_t stream) {
  const float* x   = (const float*)d_in[0];
  const int*   ew  = (const int*)d_in[1];
  const float* W1  = (const float*)d_in[2];
  const float* b1  = (const float*)d_in[3];
  const float* g1  = (const float*)d_in[4];
  const float* be1 = (const float*)d_in[5];
  const float* W2  = (const float*)d_in[6];
  const float* b2  = (const float*)d_in[7];
  const float* g4  = (const float*)d_in[8];
  const float* be4 = (const float*)d_in[9];
  const float* Wl1 = (const float*)d_in[10];
  const float* bl1 = (const float*)d_in[11];
  const float* Wl3 = (const float*)d_in[12];
  const float* bl3 = (const float*)d_in[13];
  float* out = (float*)d_out;

  char* ws = (char*)d_ws;
  const size_t OFF_OFF  = 0;          // (N+1) ints
  const size_t OFF_BASES= 400128;     // NBUCK+1 ints
  const size_t OFF_CNT  = 800256;     // CGRID x NBUCK ints (306KB)
  const size_t OFF_WL3T = 1106944;    // 16x128 bf16 (4KB)
  const size_t OFF_TOT  = 1114112;    // NBUCK ints
  const size_t OFF_STATS= 1200384;    // 4x256 f32 (zeroed in k_detect)
  const size_t OFF_FLAG = 1208576;
  const size_t OFF_W1T  = 1209216;    // fp8 64KB
  const size_t OFF_W2T  = 1340288;    // fp8 64KB
  const size_t OFF_WL1T = 1471360;    // bf16 64KB
  const size_t OFF_CSR  = 1536896;    // NE ints (6.4MB)
  const size_t OFF_BUFA = 7936896;    // pairs (6.4MB) aliases; h0/h2 fp8 25.6MB
  const size_t OFF_BUFB = 59136896;   // xq fp8 25.6MB aliases; h1 fp8 25.6MB
  if (ws_size < 110336896) return;

  int* off_  = (int*)(ws + OFF_OFF);
  int* bases_= (int*)(ws + OFF_BASES);
  int* cnt_  = (int*)(ws + OFF_CNT);
  int* tot_  = (int*)(ws + OFF_TOT);
  float* sum1 = (float*)(ws + OFF_STATS);
  float* ssq1 = sum1 + 256;
  float* sum4 = sum1 + 512;
  float* ssq4 = sum1 + 768;
  int* flag_ = (int*)(ws + OFF_FLAG);
  unsigned char* W1T8 = (unsigned char*)(ws + OFF_W1T);
  unsigned char* W2T8 = (unsigned char*)(ws + OFF_W2T);
  short* Wl1T = (short*)(ws + OFF_WL1T);
  short* Wl3T = (short*)(ws + OFF_WL3T);
  int* csr_   = (int*)(ws + OFF_CSR);
  unsigned char* bufA = (unsigned char*)(ws + OFF_BUFA);
  unsigned char* bufB = (unsigned char*)(ws + OFF_BUFB);
  int* pairs_ = (int*)(ws + OFF_BUFA);  // alias: dead before k_agg2 writes bufA
  void* xq    = (void*)bufB;            // alias: dead before GEMM1 writes bufB

  k_detect<<<1, 256, 0, stream>>>(ew, flag_, sum1);
  k_cvtW<<<641, 256, 0, stream>>>(W1, W2, Wl1, Wl3, W1T8, W2T8, Wl1T, Wl3T);
  k_cvtX<<<12500, 256, 0, stream>>>(x, xq);
  k_count<<<CGRID, 1024, 0, stream>>>(ew, flag_, cnt_);
  k_cscan<<<196, 256, 0, stream>>>(cnt_, tot_);
  k_bscan<<<1, 1024, 0, stream>>>(tot_, bases_, off_);
  k_scatter<<<CGRID, 1024, 0, stream>>>(ew, flag_, cnt_, bases_, pairs_);
  k_bsort<<<NBUCK, 256, 0, stream>>>(pairs_, bases_, off_, csr_);
  k_agg2<<<25000, 256, 0, stream>>>(xq, off_, csr_, bufA);
  k_gemm8<0, 0, 1><<<1564, 256, 0, stream>>>(bufA, W1T8, b1, bufB, NN,
                                             nullptr, nullptr, nullptr, nullptr,
                                             sum1, ssq1);
  k_gemm8<1, 1, 1><<<1564, 256, 0, stream>>>(bufB, W2T8, b2, bufA, NN,
                                             sum1, ssq1, g1, be1, sum4, ssq4);
  k_head<<<782, 256, 0, stream>>>(bufA, x, Wl1T, bl1, Wl3T, bl3,
                                  sum4, ssq4, g4, be4, out, NN);
}

// Round 14
// 248.881 us; speedup vs baseline: 1.5730x; 1.0352x over previous
//
#include <hip/hip_runtime.h>

constexpr int NN = 100000;   // nodes
constexpr int NE = 1600000;  // edges
constexpr int NBUCK = 782;   // ceil(NN/128)
constexpr int CGRID = 98;    // count/scatter blocks (98*16384 >= NE)
// phase1 block ranges (1024-thread blocks)
constexpr int PH_CVTX = 3125;          // 3125 blocks: cvtX (3.2M chunks / 1024)
constexpr int PH_CNT_END = PH_CVTX + CGRID;      // 98 count blocks
constexpr int PH_GRID = PH_CNT_END + 161;        // 161 cvtW blocks (641 units / 4)

typedef __attribute__((ext_vector_type(4))) float  f32x4;
typedef __attribute__((ext_vector_type(2))) float  f32x2;
typedef __attribute__((ext_vector_type(8))) short  bf16x8;

__device__ __forceinline__ float bf2f(unsigned short u) {
  union { unsigned int i; float f; } c;
  c.i = ((unsigned int)u) << 16;
  return c.f;
}
__device__ __forceinline__ short f2bf(float f) {
  union { float f; unsigned int i; } c; c.f = f;
  unsigned int i = c.i + 0x7fffu + ((c.i >> 16) & 1u);
  return (short)(i >> 16);
}
__device__ __forceinline__ unsigned char f2fp8(float f) {
  int w = __builtin_amdgcn_cvt_pk_fp8_f32(f, 0.f, 0, false);
  return (unsigned char)(w & 0xff);
}
__device__ __forceinline__ void up4(int wv, float* f) {
  f32x2 a = __builtin_amdgcn_cvt_pk_f32_fp8(wv, false);
  f32x2 b = __builtin_amdgcn_cvt_pk_f32_fp8(wv, true);
  f[0] = a[0]; f[1] = a[1]; f[2] = b[0]; f[3] = b[1];
}

// async global->LDS, 16B per lane; LDS dest is wave-uniform base + lane*16
__device__ __forceinline__ void gload16(const void* g, void* l) {
  __builtin_amdgcn_global_load_lds(
      (const __attribute__((address_space(1))) unsigned int*)g,
      (__attribute__((address_space(3))) unsigned int*)l, 16, 0, 0);
}

// ============================================================================
// phase1: fused independent front-end. Block ranges:
//   [0, 3125)        cvtX  : x f32 -> xq fp8 (linear [NN][256B])
//   [3125, 3223)     count : per-block bucket histogram (m64 detected inline)
//   [3223, 3384)     cvtW  : weight converts (4 old 256-thr units per block);
//                            block 3223 also zeroes the 1024 stats floats
// ============================================================================
__global__ __launch_bounds__(1024) void k_phase1(
    const float* __restrict__ x, void* __restrict__ xq,
    const int* __restrict__ ew, int* __restrict__ cntmat,
    const float* __restrict__ W1, const float* __restrict__ W2,
    const float* __restrict__ Wl1, const float* __restrict__ Wl3,
    unsigned char* __restrict__ W1T8, unsigned char* __restrict__ W2T8,
    short* __restrict__ Wl1T, short* __restrict__ Wl3T,
    float* __restrict__ zst) {
  __shared__ int lcnt[NBUCK];
  __shared__ int badsh;
  int bid = blockIdx.x, tid = threadIdx.x;
  if (bid < PH_CVTX) {
    int c = bid * 1024 + tid;  // chunk of 8 cols
    float4 a = ((const float4*)x)[2 * (size_t)c];
    float4 b = ((const float4*)x)[2 * (size_t)c + 1];
    int p0 = 0, p1 = 0;
    p0 = __builtin_amdgcn_cvt_pk_fp8_f32(a.x, a.y, p0, false);
    p0 = __builtin_amdgcn_cvt_pk_fp8_f32(a.z, a.w, p0, true);
    p1 = __builtin_amdgcn_cvt_pk_fp8_f32(b.x, b.y, p1, false);
    p1 = __builtin_amdgcn_cvt_pk_fp8_f32(b.z, b.w, p1, true);
    ((int2*)xq)[c] = make_int2(p0, p1);
  } else if (bid < PH_CNT_END) {
    int cb = bid - PH_CVTX;
    if (tid == 0) badsh = 0;
    for (int i = tid; i < NBUCK; i += 1024) lcnt[i] = 0;
    __syncthreads();
    int nz = 0;
    for (int i = tid; i < 2048; i += 1024) nz |= ew[2 * i + 1];
    if (nz) atomicOr(&badsh, 1);
    __syncthreads();
    int m64 = (badsh == 0);
    int base = cb * 16384;
#pragma unroll
    for (int u = 0; u < 16; u++) {
      int e = base + u * 1024 + tid;
      if (e < NE) {
        int d = m64 ? ew[2 * (NE + e)] : ew[NE + e];
        atomicAdd(&lcnt[d >> 7], 1);
      }
    }
    __syncthreads();
    for (int i = tid; i < NBUCK; i += 1024) cntmat[cb * NBUCK + i] = lcnt[i];
  } else {
    int wb = bid - PH_CNT_END;
    if (wb == 0) zst[tid] = 0.f;  // 4x256 stats floats
    int b = wb * 4 + (tid >> 8), t = tid & 255;
    if (b < 641) {
      if (b < 256)       W1T8[b * 256 + t]       = f2fp8(W1[t * 256 + b]);
      else if (b < 512){ int n = b - 256; W2T8[n * 256 + t] = f2fp8(W2[t * 256 + n]); }
      else if (b < 640){ int n = b - 512; Wl1T[n * 256 + t] = f2bf(Wl1[t * 128 + n]); }
      else {
        if (t < 128) {
#pragma unroll
          for (int c = 0; c < 16; ++c)
            Wl3T[c * 128 + t] = (c < 10) ? f2bf(Wl3[t * 10 + c]) : (short)0;
        }
      }
    }
  }
}

// ---- pass 2a: per-bucket scan across the 98 blocks (one wave per bucket).
// Bucket total computed CONVERGENTLY (all lanes run the shuffles, before any
// branch); lane 63 read is valid because v1 is zero-padded past g=97. ----
__global__ __launch_bounds__(256) void k_cscan(int* __restrict__ cntmat,
                                               int* __restrict__ tot) {
  int wid = (blockIdx.x * 256 + threadIdx.x) >> 6;  // bucket
  int lane = threadIdx.x & 63;
  if (wid >= NBUCK) return;   // whole-wave uniform exit (wid is per-wave)
  int v0 = (lane < CGRID) ? cntmat[lane * NBUCK + wid] : 0;
  int v1 = (lane + 64 < CGRID) ? cntmat[(lane + 64) * NBUCK + wid] : 0;
  int s0 = v0;
#pragma unroll
  for (int o = 1; o < 64; o <<= 1) { int u = __shfl_up(s0, o); if (lane >= o) s0 += u; }
  int s1 = v1;
#pragma unroll
  for (int o = 1; o < 64; o <<= 1) { int u = __shfl_up(s1, o); if (lane >= o) s1 += u; }
  int t0 = __shfl(s0, 63);       // total of g=0..63   (convergent)
  int t1 = __shfl(s1, 63);       // total of g=64..97  (convergent, zero-padded)
  if (lane < CGRID) cntmat[lane * NBUCK + wid] = s0 - v0;            // exclusive
  if (lane + 64 < CGRID) cntmat[(lane + 64) * NBUCK + wid] = t0 + s1 - v1;
  if (lane == 0) tot[wid] = t0 + t1;
}

// ---- pass 2b: scan bucket totals -> bases ----
__global__ __launch_bounds__(1024) void k_bscan(const int* __restrict__ tot,
                                                int* __restrict__ bases,
                                                int* __restrict__ off_) {
  __shared__ int s[1024];
  int t = threadIdx.x;
  int v = (t < NBUCK) ? tot[t] : 0;
  s[t] = v; __syncthreads();
  for (int o = 1; o < 1024; o <<= 1) {
    int u = (t >= o) ? s[t - o] : 0;
    __syncthreads();
    s[t] += u;
    __syncthreads();
  }
  if (t < NBUCK) bases[t] = s[t] - v;  // exclusive
  if (t == 0) { bases[NBUCK] = NE; off_[NN] = NE; }
}

// ---- pass 3: dense bucketed scatter of packed (src | ld<<17); m64 inline ----
__global__ __launch_bounds__(1024) void k_scatter(const int* __restrict__ ew,
                                                  const int* __restrict__ cntmat,
                                                  const int* __restrict__ bases,
                                                  int* __restrict__ pairs) {
  __shared__ int lcur[NBUCK];
  __shared__ int badsh;
  int t = threadIdx.x;
  if (t == 0) badsh = 0;
  for (int i = t; i < NBUCK; i += 1024)
    lcur[i] = bases[i] + cntmat[blockIdx.x * NBUCK + i];
  __syncthreads();
  int nz = 0;
  for (int i = t; i < 2048; i += 1024) nz |= ew[2 * i + 1];
  if (nz) atomicOr(&badsh, 1);
  __syncthreads();
  int m64 = (badsh == 0);
  int base = blockIdx.x * 16384;
#pragma unroll
  for (int u = 0; u < 16; u++) {
    int e = base + u * 1024 + t;
    if (e < NE) {
      int d = m64 ? ew[2 * (NE + e)] : ew[NE + e];
      int s = m64 ? ew[2 * e] : ew[e];
      int slot = atomicAdd(&lcur[d >> 7], 1);
      pairs[slot] = s | ((d & 127) << 17);
    }
  }
}

// ---- pass 4: per-bucket counting sort in LDS -> off_ + csr ----
__global__ __launch_bounds__(256) void k_bsort(const int* __restrict__ pairs,
                                               const int* __restrict__ bases,
                                               int* __restrict__ off_,
                                               int* __restrict__ csr) {
  __shared__ int lcnt[128], lofs[128], lcur[128];
  int b = blockIdx.x, t = threadIdx.x;
  int s0 = bases[b], s1 = bases[b + 1];
  if (t < 128) lcnt[t] = 0;
  __syncthreads();
  for (int j = s0 + t; j < s1; j += 256) atomicAdd(&lcnt[(pairs[j] >> 17) & 127], 1);
  __syncthreads();
  int v = (t < 128) ? lcnt[t] : 0;
  if (t < 128) lofs[t] = v;
  __syncthreads();
  for (int o = 1; o < 128; o <<= 1) {
    int u = (t >= o && t < 128) ? lofs[t - o] : 0;
    __syncthreads();
    if (t < 128) lofs[t] += u;
    __syncthreads();
  }
  if (t < 128) {
    int ex = lofs[t] - v;  // exclusive
    lcur[t] = ex;
    int node = b * 128 + t;
    if (node < NN) off_[node] = s0 + ex;
  }
  __syncthreads();
  for (int j = s0 + t; j < s1; j += 256) {
    int p = pairs[j];
    int slot = atomicAdd(&lcur[(p >> 17) & 127], 1);
    csr[s0 + slot] = p & 0x1FFFF;
  }
}

// one WAVE per node, lane owns 4 columns; fp8 in, fp8 out (proven form)
__global__ __launch_bounds__(256) void k_agg2(const void* __restrict__ xq,
                                              const int* __restrict__ off_,
                                              const int* __restrict__ csr,
                                              unsigned char* __restrict__ h0) {
  int node = blockIdx.x * 4 + (threadIdx.x >> 6);  // grid 25000 exact
  int lane = threadIdx.x & 63;
  const unsigned char* xb = (const unsigned char*)xq;
  size_t boff = (size_t)lane * 4;  // byte offset within 256B row
  int s0 = off_[node], s1 = off_[node + 1];
  int sw = *(const int*)(xb + (size_t)node * 256 + boff);
  f32x2 slo = __builtin_amdgcn_cvt_pk_f32_fp8(sw, false);
  f32x2 shi = __builtin_amdgcn_cvt_pk_f32_fp8(sw, true);
  float a0 = slo[0], a1 = slo[1], a2 = shi[0], a3 = shi[1];
  int j = s0;
  while (j + 8 <= s1) {
    int idx[8];
#pragma unroll
    for (int u = 0; u < 8; u++) idx[u] = csr[j + u];
    int w[8];
#pragma unroll
    for (int u = 0; u < 8; u++) w[u] = *(const int*)(xb + (size_t)idx[u] * 256 + boff);
#pragma unroll
    for (int u = 0; u < 8; u++) {
      f32x2 lo = __builtin_amdgcn_cvt_pk_f32_fp8(w[u], false);
      f32x2 hi = __builtin_amdgcn_cvt_pk_f32_fp8(w[u], true);
      a0 += lo[0]; a1 += lo[1]; a2 += hi[0]; a3 += hi[1];
    }
    j += 8;
  }
  if (j + 4 <= s1) {
    int idx[4];
#pragma unroll
    for (int u = 0; u < 4; u++) idx[u] = csr[j + u];
    int w[4];
#pragma unroll
    for (int u = 0; u < 4; u++) w[u] = *(const int*)(xb + (size_t)idx[u] * 256 + boff);
#pragma unroll
    for (int u = 0; u < 4; u++) {
      f32x2 lo = __builtin_amdgcn_cvt_pk_f32_fp8(w[u], false);
      f32x2 hi = __builtin_amdgcn_cvt_pk_f32_fp8(w[u], true);
      a0 += lo[0]; a1 += lo[1]; a2 += hi[0]; a3 += hi[1];
    }
    j += 4;
  }
  for (; j < s1; j++) {
    int s = csr[j];
    int w = *(const int*)(xb + (size_t)s * 256 + boff);
    f32x2 lo = __builtin_amdgcn_cvt_pk_f32_fp8(w, false);
    f32x2 hi = __builtin_amdgcn_cvt_pk_f32_fp8(w, true);
    a0 += lo[0]; a1 += lo[1]; a2 += hi[0]; a3 += hi[1];
  }
  int o = 0;
  o = __builtin_amdgcn_cvt_pk_fp8_f32(a0, a1, o, false);
  o = __builtin_amdgcn_cvt_pk_fp8_f32(a2, a3, o, true);
  ((int*)h0)[(size_t)node * 64 + lane] = o;
}

// ============================================================================
// fp8 MFMA GEMM, 128x128 tile, BK=64 (64B/row), double-buffered.
// TIN=1: bn scale/shift from raw sums in preamble; A'=fp8(relu(bn(A))) during
// reg staging (issue-early / write-late). STATS: col sum/ssq of output.
// ============================================================================
template <int ACT, int TIN, int STATS>
__global__ __launch_bounds__(256, 2) void k_gemm8(
    const unsigned char* __restrict__ A, const unsigned char* __restrict__ BT,
    const float* __restrict__ bias, unsigned char* __restrict__ C, int M,
    const float* __restrict__ tsum, const float* __restrict__ tssq,
    const float* __restrict__ tg, const float* __restrict__ tbe,
    float* __restrict__ gsum, float* __restrict__ gssq) {
  __shared__ char smem[32768];
  __shared__ float lsc[256], lsh[256];
  __shared__ float lsum[128], lssq[128];
  int tid = threadIdx.x, lane = tid & 63, w = tid >> 6;
  if (TIN) {
    float mu = tsum[tid] / (float)M;
    float var = tssq[tid] / (float)M - mu * mu;
    float rs = rsqrtf(var + 1e-5f);
    float sc = tg[tid] * rs;
    lsc[tid] = sc; lsh[tid] = tbe[tid] - mu * sc;
  }
  if (STATS && tid < 128) { lsum[tid] = 0.f; lssq[tid] = 0.f; }
  int bm = blockIdx.x >> 1, bn = blockIdx.x & 1;
  int bm0 = bm * 128, bn0 = bn * 128;
  int wm = w >> 1, wn = w & 1;
  int lr = lane & 15, lg = lane >> 4;
  f32x4 acc[4][4] = {};
  __syncthreads();

  int4 stg[2];

#pragma unroll 1
  for (int it = 0; it < 4; ++it) {
    int b = it & 1;
    if (it == 0) {
      if (TIN) {
#pragma unroll
        for (int i = 0; i < 2; ++i) {
          int p = i * 256 + tid, unit = p >> 3, u = (p & 7) ^ (unit & 7);
          int srow = unit * 2 + (u >> 2), slot = u & 3;
          int grow = bm0 + srow; if (grow > M - 1) grow = M - 1;
          stg[i] = *(const int4*)(A + (size_t)grow * 256 + slot * 16);
        }
      } else {
#pragma unroll
        for (int q = 0; q < 2; ++q) {
          int wc = w * 2 + q;
          int p = wc * 64 + lane, unit = p >> 3, u = (p & 7) ^ (unit & 7);
          int srow = unit * 2 + (u >> 2), slot = u & 3;
          int grow = bm0 + srow; if (grow > M - 1) grow = M - 1;
          gload16(A + (size_t)grow * 256 + slot * 16, smem + wc * 1024);
        }
      }
#pragma unroll
      for (int q = 0; q < 2; ++q) {
        int wc = w * 2 + q;
        int p = wc * 64 + lane, unit = p >> 3, u = (p & 7) ^ (unit & 7);
        int srow = unit * 2 + (u >> 2), slot = u & 3;
        gload16(BT + (size_t)(bn0 + srow) * 256 + slot * 16, smem + 8192 + wc * 1024);
      }
      if (TIN) {
#pragma unroll
        for (int i = 0; i < 2; ++i) {
          int p = i * 256 + tid, unit = p >> 3, u = (p & 7) ^ (unit & 7);
          int slot = u & 3;
          int k0 = slot * 16;
          float f[16];
          up4(stg[i].x, f); up4(stg[i].y, f + 4); up4(stg[i].z, f + 8); up4(stg[i].w, f + 12);
#pragma unroll
          for (int jj = 0; jj < 16; ++jj) f[jj] = fmaxf(f[jj] * lsc[k0 + jj] + lsh[k0 + jj], 0.f);
          int w0 = 0, w1 = 0, w2 = 0, w3 = 0;
          w0 = __builtin_amdgcn_cvt_pk_fp8_f32(f[0], f[1], w0, false);
          w0 = __builtin_amdgcn_cvt_pk_fp8_f32(f[2], f[3], w0, true);
          w1 = __builtin_amdgcn_cvt_pk_fp8_f32(f[4], f[5], w1, false);
          w1 = __builtin_amdgcn_cvt_pk_fp8_f32(f[6], f[7], w1, true);
          w2 = __builtin_amdgcn_cvt_pk_fp8_f32(f[8], f[9], w2, false);
          w2 = __builtin_amdgcn_cvt_pk_fp8_f32(f[10], f[11], w2, true);
          w3 = __builtin_amdgcn_cvt_pk_fp8_f32(f[12], f[13], w3, false);
          w3 = __builtin_amdgcn_cvt_pk_fp8_f32(f[14], f[15], w3, true);
          *(int4*)(smem + p * 16) = make_int4(w0, w1, w2, w3);
        }
      }
      __syncthreads();
    }
    int ktn = (it + 1) * 64;
    if (it < 3) {
      char* nb = smem + (b ^ 1) * 16384;
      if (TIN) {
#pragma unroll
        for (int i = 0; i < 2; ++i) {
          int p = i * 256 + tid, unit = p >> 3, u = (p & 7) ^ (unit & 7);
          int srow = unit * 2 + (u >> 2), slot = u & 3;
          int grow = bm0 + srow; if (grow > M - 1) grow = M - 1;
          stg[i] = *(const int4*)(A + (size_t)grow * 256 + ktn + slot * 16);
        }
      } else {
#pragma unroll
        for (int q = 0; q < 2; ++q) {
          int wc = w * 2 + q;
          int p = wc * 64 + lane, unit = p >> 3, u = (p & 7) ^ (unit & 7);
          int srow = unit * 2 + (u >> 2), slot = u & 3;
          int grow = bm0 + srow; if (grow > M - 1) grow = M - 1;
          gload16(A + (size_t)grow * 256 + ktn + slot * 16, nb + wc * 1024);
        }
      }
#pragma unroll
      for (int q = 0; q < 2; ++q) {
        int wc = w * 2 + q;
        int p = wc * 64 + lane, unit = p >> 3, u = (p & 7) ^ (unit & 7);
        int srow = unit * 2 + (u >> 2), slot = u & 3;
        gload16(BT + (size_t)(bn0 + srow) * 256 + ktn + slot * 16, nb + 8192 + wc * 1024);
      }
    }
    const char* sa = smem + b * 16384;
    const char* sb = sa + 8192;
#pragma unroll
    for (int ks = 0; ks < 2; ++ks) {
      long af[4], bfr[4];
#pragma unroll
      for (int mi = 0; mi < 4; ++mi) {
        int row = wm * 64 + mi * 16 + lr;
        int unit = row >> 1;
        int u = ((row & 1) * 4 + ks * 2 + (lg >> 1)) ^ (unit & 7);
        af[mi] = *(const long*)(sa + unit * 128 + u * 16 + (lg & 1) * 8);
      }
#pragma unroll
      for (int ni = 0; ni < 4; ++ni) {
        int row = wn * 64 + ni * 16 + lr;
        int unit = row >> 1;
        int u = ((row & 1) * 4 + ks * 2 + (lg >> 1)) ^ (unit & 7);
        bfr[ni] = *(const long*)(sb + unit * 128 + u * 16 + (lg & 1) * 8);
      }
#pragma unroll
      for (int mi = 0; mi < 4; ++mi)
#pragma unroll
        for (int ni = 0; ni < 4; ++ni)
          acc[mi][ni] = __builtin_amdgcn_mfma_f32_16x16x32_fp8_fp8(af[mi], bfr[ni], acc[mi][ni], 0, 0, 0);
    }
    if (TIN && it < 3) {
      char* nb = smem + (b ^ 1) * 16384;
#pragma unroll
      for (int i = 0; i < 2; ++i) {
        int p = i * 256 + tid, unit = p >> 3, u = (p & 7) ^ (unit & 7);
        int slot = u & 3;
        int k0 = ktn + slot * 16;
        float f[16];
        up4(stg[i].x, f); up4(stg[i].y, f + 4); up4(stg[i].z, f + 8); up4(stg[i].w, f + 12);
#pragma unroll
        for (int jj = 0; jj < 16; ++jj) f[jj] = fmaxf(f[jj] * lsc[k0 + jj] + lsh[k0 + jj], 0.f);
        int w0 = 0, w1 = 0, w2 = 0, w3 = 0;
        w0 = __builtin_amdgcn_cvt_pk_fp8_f32(f[0], f[1], w0, false);
        w0 = __builtin_amdgcn_cvt_pk_fp8_f32(f[2], f[3], w0, true);
        w1 = __builtin_amdgcn_cvt_pk_fp8_f32(f[4], f[5], w1, false);
        w1 = __builtin_amdgcn_cvt_pk_fp8_f32(f[6], f[7], w1, true);
        w2 = __builtin_amdgcn_cvt_pk_fp8_f32(f[8], f[9], w2, false);
        w2 = __builtin_amdgcn_cvt_pk_fp8_f32(f[10], f[11], w2, true);
        w3 = __builtin_amdgcn_cvt_pk_fp8_f32(f[12], f[13], w3, false);
        w3 = __builtin_amdgcn_cvt_pk_fp8_f32(f[14], f[15], w3, true);
        *(int4*)(nb + p * 16) = make_int4(w0, w1, w2, w3);
      }
    }
    __syncthreads();
  }

  unsigned char* zs = (unsigned char*)smem;  // [128][144] fp8
#pragma unroll
  for (int ni = 0; ni < 4; ++ni) {
    int col = wn * 64 + ni * 16 + lr;
    float bv = bias[bn0 + col];
    float ps = 0.f, pq = 0.f;
#pragma unroll
    for (int mi = 0; mi < 4; ++mi) {
#pragma unroll
      for (int r = 0; r < 4; ++r) {
        int row = wm * 64 + mi * 16 + lg * 4 + r;
        float tv = acc[mi][ni][r] + bv;
        if (ACT == 1) tv = tv > 0.f ? tv : 0.01f * tv;  // lrelu(lrelu(t,0.1),0.1)
        if (STATS && (bm0 + row) < M) { ps += tv; pq += tv * tv; }
        zs[row * 144 + col] = f2fp8(tv);
      }
    }
    if (STATS) {
      ps += __shfl_xor(ps, 16); pq += __shfl_xor(pq, 16);
      ps += __shfl_xor(ps, 32); pq += __shfl_xor(pq, 32);
      if (lane < 16) {
        atomicAdd(&lsum[wn * 64 + ni * 16 + lane], ps);
        atomicAdd(&lssq[wn * 64 + ni * 16 + lane], pq);
      }
    }
  }
  __syncthreads();
  {
    int row = tid >> 1;
    int grow = bm0 + row;
    if (grow < M) {
#pragma unroll
      for (int i = 0; i < 4; ++i) {
        int cs = (tid & 1) * 64 + i * 16;
        int4 v = *(const int4*)(zs + row * 144 + cs);
        *(int4*)(C + (size_t)grow * 256 + bn0 + cs) = v;
      }
    }
  }
  if (STATS) {
    if (tid < 128) {
      atomicAdd(&gsum[bn0 + tid], lsum[tid]);
      atomicAdd(&gssq[bn0 + tid], lssq[tid]);
    }
  }
}

// ============================================================================
// head: bn4 scale/shift from raw sums; A' = bf16(x + 0.01*lrelu(bn4(V[fp8])));
// z = lrelu(A' @ Wl1 + bl1); out = z @ Wl3 + bl3 via 128x16 MFMA.
// ============================================================================
__global__ __launch_bounds__(256, 2) void k_head(const unsigned char* __restrict__ Vq,
                                                 const float* __restrict__ x,
                                                 const short* __restrict__ BT,
                                                 const float* __restrict__ bl1,
                                                 const short* __restrict__ wl3t,
                                                 const float* __restrict__ bl3,
                                                 const float* __restrict__ tsum,
                                                 const float* __restrict__ tssq,
                                                 const float* __restrict__ tg,
                                                 const float* __restrict__ tbe,
                                                 float* __restrict__ out, int M) {
  __shared__ char smem[65536];
  __shared__ float lsc[256], lsh[256];
  __shared__ short wl3s[2048];
  int tid = threadIdx.x;
  int lane = tid & 63, w = tid >> 6;
  {
    float mu = tsum[tid] / (float)M;
    float var = tssq[tid] / (float)M - mu * mu;
    float rs = rsqrtf(var + 1e-5f);
    float sc = tg[tid] * rs;
    lsc[tid] = sc; lsh[tid] = tbe[tid] - mu * sc;
  }
  {
    int p = w * 64 + lane;
    gload16(wl3t + (size_t)p * 8, (char*)wl3s + w * 1024);
  }
  int bm0 = blockIdx.x * 128;
  int wm = w >> 1, wn = w & 1;
  int lr = lane & 15, lg = lane >> 4;
  f32x4 acc[4][4] = {};
  __syncthreads();

  int2 stgv[4];
  float stgx[4][8];

#pragma unroll 1
  for (int it = 0; it < 4; ++it) {
    int b = it & 1;
    if (it == 0) {
#pragma unroll
      for (int i = 0; i < 4; ++i) {
        int p = tid + 256 * i, row = p >> 3, s = (p & 7) ^ (row & 7);
        int grow = bm0 + row; if (grow > M - 1) grow = M - 1;
        size_t base = (size_t)grow * 256 + s * 8;
        stgv[i] = *(const int2*)(Vq + base);
        *(float4*)&stgx[i][0] = *(const float4*)(x + base);
        *(float4*)&stgx[i][4] = *(const float4*)(x + base + 4);
      }
#pragma unroll
      for (int q = 0; q < 4; ++q) {
        int wc = w * 4 + q;
        int p = wc * 64 + lane, row = p >> 3, s = (p & 7) ^ (row & 7);
        gload16(BT + (size_t)row * 256 + s * 8, smem + 16384 + wc * 1024);
      }
#pragma unroll
      for (int i = 0; i < 4; ++i) {
        int p = tid + 256 * i, row = p >> 3, s = (p & 7) ^ (row & 7);
        int k0 = s * 8;
        float fv[8];
        up4(stgv[i].x, fv); up4(stgv[i].y, fv + 4);
        bf16x8 o;
#pragma unroll
        for (int jj = 0; jj < 8; ++jj) {
          float f = fv[jj] * lsc[k0 + jj] + lsh[k0 + jj];
          f = f > 0.f ? f : 0.1f * f;
          o[jj] = f2bf(stgx[i][jj] + 0.01f * f);
        }
        *(bf16x8*)(smem + p * 16) = o;
      }
      __syncthreads();
    }
    int ktn = (it + 1) * 64;
    if (it < 3) {
      char* nb = smem + (b ^ 1) * 32768;
#pragma unroll
      for (int i = 0; i < 4; ++i) {
        int p = tid + 256 * i, row = p >> 3, s = (p & 7) ^ (row & 7);
        int grow = bm0 + row; if (grow > M - 1) grow = M - 1;
        size_t base = (size_t)grow * 256 + ktn + s * 8;
        stgv[i] = *(const int2*)(Vq + base);
        *(float4*)&stgx[i][0] = *(const float4*)(x + base);
        *(float4*)&stgx[i][4] = *(const float4*)(x + base + 4);
      }
#pragma unroll
      for (int q = 0; q < 4; ++q) {
        int wc = w * 4 + q;
        int p = wc * 64 + lane, row = p >> 3, s = (p & 7) ^ (row & 7);
        gload16(BT + (size_t)row * 256 + ktn + s * 8, nb + 16384 + wc * 1024);
      }
    }
    const char* sa = smem + b * 32768;
    const char* sb = sa + 16384;
#pragma unroll
    for (int ks = 0; ks < 2; ++ks) {
      bf16x8 af[4], bfr[4];
#pragma unroll
      for (int mi = 0; mi < 4; ++mi) {
        int row = wm * 64 + mi * 16 + lr;
        int q = (lg + 4 * ks) ^ (row & 7);
        af[mi] = *(const bf16x8*)(sa + row * 128 + q * 16);
      }
#pragma unroll
      for (int ni = 0; ni < 4; ++ni) {
        int row = wn * 64 + ni * 16 + lr;
        int q = (lg + 4 * ks) ^ (row & 7);
        bfr[ni] = *(const bf16x8*)(sb + row * 128 + q * 16);
      }
#pragma unroll
      for (int mi = 0; mi < 4; ++mi)
#pragma unroll
        for (int ni = 0; ni < 4; ++ni)
          acc[mi][ni] = __builtin_amdgcn_mfma_f32_16x16x32_bf16(af[mi], bfr[ni], acc[mi][ni], 0, 0, 0);
    }
    if (it < 3) {
      char* nb = smem + (b ^ 1) * 32768;
#pragma unroll
      for (int i = 0; i < 4; ++i) {
        int p = tid + 256 * i, row = p >> 3, s = (p & 7) ^ (row & 7);
        int k0 = ktn + s * 8;
        float fv[8];
        up4(stgv[i].x, fv); up4(stgv[i].y, fv + 4);
        bf16x8 o;
#pragma unroll
        for (int jj = 0; jj < 8; ++jj) {
          float f = fv[jj] * lsc[k0 + jj] + lsh[k0 + jj];
          f = f > 0.f ? f : 0.1f * f;
          o[jj] = f2bf(stgx[i][jj] + 0.01f * f);
        }
        *(bf16x8*)(nb + p * 16) = o;
      }
    }
    __syncthreads();
  }

  short* zs = (short*)smem;  // [128][136] bf16
#pragma unroll
  for (int ni = 0; ni < 4; ++ni) {
    int col = wn * 64 + ni * 16 + lr;
    float bv = bl1[col];
#pragma unroll
    for (int mi = 0; mi < 4; ++mi) {
#pragma unroll
      for (int r = 0; r < 4; ++r) {
        int row = wm * 64 + mi * 16 + lg * 4 + r;
        float tv = acc[mi][ni][r] + bv;
        tv = tv > 0.f ? tv : 0.1f * tv;
        zs[row * 136 + col] = f2bf(tv);
      }
    }
  }
  __syncthreads();

  f32x4 acc2[2] = {};
#pragma unroll
  for (int kk = 0; kk < 4; ++kk) {
    bf16x8 bfr = *(const bf16x8*)((const char*)wl3s + lr * 256 + (kk * 4 + lg) * 16);
#pragma unroll
    for (int m = 0; m < 2; ++m) {
      int row = (w * 2 + m) * 16 + lr;
      bf16x8 af = *(const bf16x8*)((const char*)zs + row * 272 + (kk * 4 + lg) * 16);
      acc2[m] = __builtin_amdgcn_mfma_f32_16x16x32_bf16(af, bfr, acc2[m], 0, 0, 0);
    }
  }
  if (lr < 10) {
    float bv = bl3[lr];
#pragma unroll
    for (int m = 0; m < 2; ++m) {
#pragma unroll
      for (int r = 0; r < 4; ++r) {
        int row = (w * 2 + m) * 16 + lg * 4 + r;
        int grow = bm0 + row;
        if (grow < M) out[(size_t)grow * 10 + lr] = acc2[m][r] + bv;
      }
    }
  }
}

extern "C" void kernel_launch(void* const* d_in, const int* in_sizes, int n_in,
                              void* d_out, int out_size, void* d_ws, size_t ws_size,
                              hipStream_t stream) {
  const float* x   = (const float*)d_in[0];
  const int*   ew  = (const int*)d_in[1];
  const float* W1  = (const float*)d_in[2];
  const float* b1  = (const float*)d_in[3];
  const float* g1  = (const float*)d_in[4];
  const float* be1 = (const float*)d_in[5];
  const float* W2  = (const float*)d_in[6];
  const float* b2  = (const float*)d_in[7];
  const float* g4  = (const float*)d_in[8];
  const float* be4 = (const float*)d_in[9];
  const float* Wl1 = (const float*)d_in[10];
  const float* bl1 = (const float*)d_in[11];
  const float* Wl3 = (const float*)d_in[12];
  const float* bl3 = (const float*)d_in[13];
  float* out = (float*)d_out;

  char* ws = (char*)d_ws;
  const size_t OFF_OFF  = 0;          // (N+1) ints
  const size_t OFF_BASES= 400128;     // NBUCK+1 ints
  const size_t OFF_CNT  = 800256;     // CGRID x NBUCK ints (306KB)
  const size_t OFF_WL3T = 1106944;    // 16x128 bf16 (4KB)
  const size_t OFF_TOT  = 1114112;    // NBUCK ints
  const size_t OFF_STATS= 1200384;    // 4x256 f32 (zeroed in phase1)
  const size_t OFF_W1T  = 1209216;    // fp8 64KB
  const size_t OFF_W2T  = 1340288;    // fp8 64KB
  const size_t OFF_WL1T = 1471360;    // bf16 64KB
  const size_t OFF_CSR  = 1536896;    // NE ints (6.4MB)
  const size_t OFF_BUFA = 7936896;    // pairs (6.4MB) aliases; h0/h2 fp8 25.6MB
  const size_t OFF_BUFB = 59136896;   // xq fp8 25.6MB aliases; h1 fp8 25.6MB
  if (ws_size < 110336896) return;

  int* off_  = (int*)(ws + OFF_OFF);
  int* bases_= (int*)(ws + OFF_BASES);
  int* cnt_  = (int*)(ws + OFF_CNT);
  int* tot_  = (int*)(ws + OFF_TOT);
  float* sum1 = (float*)(ws + OFF_STATS);
  float* ssq1 = sum1 + 256;
  float* sum4 = sum1 + 512;
  float* ssq4 = sum1 + 768;
  unsigned char* W1T8 = (unsigned char*)(ws + OFF_W1T);
  unsigned char* W2T8 = (unsigned char*)(ws + OFF_W2T);
  short* Wl1T = (short*)(ws + OFF_WL1T);
  short* Wl3T = (short*)(ws + OFF_WL3T);
  int* csr_   = (int*)(ws + OFF_CSR);
  unsigned char* bufA = (unsigned char*)(ws + OFF_BUFA);
  unsigned char* bufB = (unsigned char*)(ws + OFF_BUFB);
  int* pairs_ = (int*)(ws + OFF_BUFA);  // alias: dead before k_agg2 writes bufA
  void* xq    = (void*)bufB;            // alias: dead before GEMM1 writes bufB

  k_phase1<<<PH_GRID, 1024, 0, stream>>>(x, xq, ew, cnt_, W1, W2, Wl1, Wl3,
                                         W1T8, W2T8, Wl1T, Wl3T, sum1);
  k_cscan<<<196, 256, 0, stream>>>(cnt_, tot_);
  k_bscan<<<1, 1024, 0, stream>>>(tot_, bases_, off_);
  k_scatter<<<CGRID, 1024, 0, stream>>>(ew, cnt_, bases_, pairs_);
  k_bsort<<<NBUCK, 256, 0, stream>>>(pairs_, bases_, off_, csr_);
  k_agg2<<<25000, 256, 0, stream>>>(xq, off_, csr_, bufA);
  k_gemm8<0, 0, 1><<<1564, 256, 0, stream>>>(bufA, W1T8, b1, bufB, NN,
                                             nullptr, nullptr, nullptr, nullptr,
                                             sum1, ssq1);
  k_gemm8<1, 1, 1><<<1564, 256, 0, stream>>>(bufB, W2T8, b2, bufA, NN,
                                             sum1, ssq1, g1, be1, sum4, ssq4);
  k_head<<<782, 256, 0, stream>>>(bufA, x, Wl1T, bl1, Wl3T, bl3,
                                  sum4, ssq4, g4, be4, out, NN);
}